// Round 2
// baseline (337.811 us; speedup 1.0000x reference)
//
#include <hip/hip_runtime.h>
#include <hip/hip_bf16.h>

#define NN 268
#define NE 8192
#define KP 288   // padded K (268 -> 288), shared by gemm1 / dense L / classifier

typedef short short8 __attribute__((ext_vector_type(8)));   // 8 bf16 = 4 VGPR
typedef short short4v __attribute__((ext_vector_type(4)));  // 4 bf16 = 8B
typedef float f32x4 __attribute__((ext_vector_type(4)));

__device__ __forceinline__ short f2bf(float f) {
  __hip_bfloat16 h = __float2bfloat16(f);
  return *reinterpret_cast<short*>(&h);
}

// ---------------------------------------------------------------------------
// Workspace (bytes). Peak unchanged: 56,163,328.
//   OFF_DINV  dinv f32 [128][272]          139,264
//       slot [g*272+271] doubles as the per-graph dependency counter cnt[g]
//       (written 0.f by prep each replay; n>=268 unused by math).
//   OFF_ARENA per-graph slab, 73,728 B x 128 graphs = 9,437,184
//       slab+     0: Y2t  bf16[64][288]  (gemm1 out; phase-A B-operand)
//       slab+36,864: Ut   bf16[64][288]  (A out; B's B-operand)
//       slab+     0: Yb2t bf16[32][288]  (B out; C's B-op — Y2t dead after A)
//       slab+18,432: U2t  bf16[32][288]  (C out; D's B-op — Y2t tail dead)
//       slab+36,864: H2   bf16[32][288]  (D out; cls A-op — Ut dead after B)
//       Per-graph overlays are ordered by the per-graph phase barriers, so
//       cross-graph phase skew can never alias another graph's live data.
//   OFF_WBT   WbT   bf16[192][288]          110,592
//   OFF_WC1BT Wc1bT bf16[112][288]           64,512
//   OFF_LB    Lb    bf16[128][272][288]   20,054,016
//   OFF_Y     Y     f32 [128][268][192]   26,345,472
//   OFF_W4BT  W4bT  bf16[96][64]              12,288
// ---------------------------------------------------------------------------
#define OFF_DINV  0
#define OFF_ARENA 139264
#define SLAB_S    36864     // slab stride in SHORTS (73,728 B)
#define Y2T_S     0
#define UT_S      18432
#define YB2T_S    0
#define U2T_S     9216
#define H2_S      18432
#define OFF_WBT   9576448
#define OFF_WC1BT 9687040
#define OFF_LB    9751552
#define OFF_Y     29805568
#define OFF_W4BT  56151040

// ---------------------------------------------------------------------------
// Per-graph dependency counter protocol (cnt[g] = dinv[g*272+271], zeroed by
// k_prep each graph replay — workspace poison between iterations is handled).
// Arrivals: 8 build blocks + 5 gemm1 blocks -> cheb phase A entry at >=13;
// each cheb block bumps after each phase: B>=18, C>=23, D>=28. cls is a
// separate launch (ordinary inter-kernel ordering).
// ---------------------------------------------------------------------------
__device__ __forceinline__ void graph_arrive(unsigned* c, int t) {
  __syncthreads();  // all block threads' global writes precede t0's release
  if (t == 0)
    __hip_atomic_fetch_add(c, 1u, __ATOMIC_RELEASE, __HIP_MEMORY_SCOPE_AGENT);
}

__device__ __forceinline__ void graph_wait(unsigned* c, unsigned tgt, int t) {
  if (t == 0) {
    while (__hip_atomic_load(c, __ATOMIC_RELAXED, __HIP_MEMORY_SCOPE_AGENT) < tgt)
      __builtin_amdgcn_s_sleep(16);
    (void)__hip_atomic_load(c, __ATOMIC_ACQUIRE, __HIP_MEMORY_SCOPE_AGENT);
  }
  __syncthreads();  // broadcasts t0's acquire to the block (same CU/L1)
}

// ---------------------------------------------------------------------------
// K1: fused prep. 494 blocks. (unchanged from round 1)
//   blocks [0,128):   per-graph degree in LDS -> dinv (also zeroes cnt[g]).
//   blocks [128,494): weight conversions (WbT, Wc1bT, W4bT).
// ---------------------------------------------------------------------------
__global__ __launch_bounds__(256) void k_prep(
    const int* __restrict__ ei1, const float* __restrict__ ea1,
    const int* __restrict__ ei2, const float* __restrict__ ea2,
    const float* __restrict__ W1, const float* __restrict__ Wc1,
    const float* __restrict__ W4, short* __restrict__ WbT,
    short* __restrict__ Wc1bT, short* __restrict__ W4bT,
    float* __restrict__ dinv) {
  int t = threadIdx.x;
  int b = blockIdx.x;
  if (b < 128) {
    int g = b;
    const int* ei = (g < 64) ? (ei1 + (size_t)g * 2 * NE) : (ei2 + (size_t)(g - 64) * 2 * NE);
    const float* ea = (g < 64) ? (ea1 + (size_t)g * NE) : (ea2 + (size_t)(g - 64) * NE);
    __shared__ unsigned degL[NN];
    for (int n = t; n < NN; n += 256) degL[n] = 0u;
    __syncthreads();
#pragma unroll 4
    for (int e = t; e < NE; e += 256) {
      int s = ei[e], d = ei[NE + e];
      float w = ea[e];
      if (s != d) atomicAdd(&degL[s], (unsigned)lrintf(w * 1048576.f));
    }
    __syncthreads();
    for (int n = t; n < 272; n += 256) {
      float r = 0.f;  // n>=268 (incl. the cnt slot 271) written as 0
      if (n < NN) {
        unsigned v = degL[n];
        if (v) r = rsqrtf((float)v * (1.f / 1048576.f));
      }
      dinv[(size_t)g * 272 + n] = r;
    }
  } else {
    int idx = (b - 128) * 256 + t;  // 0..93695
    if (idx < 192 * KP) {
      int n = idx / KP, kp = idx - n * KP;
      int kb = n >> 6, j = n & 63;
      float v = (kp < 268) ? W1[((size_t)kb * 268 + kp) * 64 + j] : 0.f;
      WbT[idx] = f2bf(v);
    } else if (idx < 192 * KP + 112 * KP) {
      int i2 = idx - 192 * KP;  // 0..32255
      int n = i2 / KP, k = i2 - n * KP;
      float v = (n < 100 && k < 268) ? Wc1[(size_t)k * 100 + n] : 0.f;
      Wc1bT[i2] = f2bf(v);
    } else {
      int i4 = idx - (192 * KP + 112 * KP);  // 0..6143
      int n = i4 >> 6, k = i4 & 63;          // n in [0,96), k in [0,64)
      W4bT[i4] = f2bf(W4[(((size_t)(n >> 5)) * 64 + k) * 32 + (n & 31)]);
    }
  }
}

// ---------------------------------------------------------------------------
// cheb phase body (old k_dgemm inner), output bases pre-offset per graph.
// A = Lb[g] [272][288] bf16, B = Btg [NCOLS][288] bf16. 64 rows x NCOLS.
// MODE 0: v = Y[d][O1+f] + 2*acc                      -> OutB[f][d] bf16
// MODE 2: v = relu(Y[d][O1+f]-Y[d][O2+f]+acc+bias[f]) -> OutB[f][d] (+d-pad 0)
// MODE 3: H1 = relu(...) in LDS bf16, fused H1 @ W4bT (M=64,N=96,K=64):
//           cols 0-64 -> Y[d][c]; cols 64-96 -> Y[d][c+96] + OutB2[c-64][d]
// ---------------------------------------------------------------------------
template <int NCOLS, int MODE, int O1, int O2>
__device__ void cheb_phase(
    const short* __restrict__ Lbg, const short* __restrict__ Btg,
    float* __restrict__ Yg, const float* __restrict__ bias,
    short* OutB, const short* __restrict__ W4bT, short* OutB2,
    int m0, int t, char* smem) {
  short (*As)[40] = (short(*)[40])smem;             //  5,120 B
  short (*Bs)[40] = (short(*)[40])(smem + 5120);    //  5,120 B (<=64 rows used)
  int w = t >> 6, lane = t & 63;
  int quad = lane >> 4, l16 = lane & 15;
  constexpr int NT = NCOLS / 32;   // n-tiles per wave (2 or 1)
  int mh = w & 1, nh = w >> 1;
  f32x4 acc[2][NT];
#pragma unroll
  for (int mi = 0; mi < 2; ++mi)
#pragma unroll
    for (int ni = 0; ni < NT; ++ni) acc[mi][ni] = (f32x4){0.f, 0.f, 0.f, 0.f};

  int sr = t >> 2, sko = (t & 3) * 8;
  for (int k0 = 0; k0 < KP; k0 += 32) {
    int arow = m0 + sr;
    short8 av;
    if (arow < 272) av = *(const short8*)(Lbg + (size_t)arow * KP + k0 + sko);
    else av = (short8){0, 0, 0, 0, 0, 0, 0, 0};
    *(short8*)(&As[sr][sko]) = av;
    if (sr < NCOLS)
      *(short8*)(&Bs[sr][sko]) = *(const short8*)(Btg + (size_t)sr * KP + k0 + sko);
    __syncthreads();
    short8 af[2], bfr[NT];
#pragma unroll
    for (int mi = 0; mi < 2; ++mi)
      af[mi] = *(const short8*)(&As[(mh * 2 + mi) * 16 + l16][quad * 8]);
#pragma unroll
    for (int ni = 0; ni < NT; ++ni)
      bfr[ni] = *(const short8*)(&Bs[(nh * NT + ni) * 16 + l16][quad * 8]);
#pragma unroll
    for (int mi = 0; mi < 2; ++mi)
#pragma unroll
      for (int ni = 0; ni < NT; ++ni)
        acc[mi][ni] = __builtin_amdgcn_mfma_f32_16x16x32_bf16(af[mi], bfr[ni], acc[mi][ni], 0, 0, 0);
    __syncthreads();
  }

  if constexpr (MODE != 3) {
#pragma unroll
    for (int mi = 0; mi < 2; ++mi) {
      int dbase = m0 + (mh * 2 + mi) * 16 + quad * 4;
      if (dbase < NN) {  // dbase % 4 == 0, never straddles 268
#pragma unroll
        for (int ni = 0; ni < NT; ++ni) {
          int f = (nh * NT + ni) * 16 + l16;
          f32x4 a = acc[mi][ni];
          if (MODE == 0) {
            short4v p;
#pragma unroll
            for (int reg = 0; reg < 4; ++reg)
              p[reg] = f2bf(Yg[(size_t)(dbase + reg) * 192 + O1 + f] + 2.f * a[reg]);
            *(short4v*)(OutB + (size_t)f * KP + dbase) = p;
          } else {
            short4v p;
#pragma unroll
            for (int reg = 0; reg < 4; ++reg) {
              int d = dbase + reg;
              float v = Yg[(size_t)d * 192 + O1 + f] - Yg[(size_t)d * 192 + O2 + f] +
                        a[reg] + bias[f];
              p[reg] = f2bf(fmaxf(v, 0.f));
            }
            *(short4v*)(OutB + (size_t)f * KP + dbase) = p;
          }
        }
      }
    }
    if (MODE == 2 && m0 == 256) {  // zero d-pad 268..287 of this graph's rows
      for (int i = t; i < 32 * 20; i += 256) {
        int f = i / 20, d = 268 + (i - f * 20);
        OutB[(size_t)f * KP + d] = 0;
      }
    }
  } else {
    // MODE 3: fused H1 -> LDS bf16 -> MFMA @ W4bT -> Yb
    short (*H1s)[72] = (short(*)[72])(smem + 10240);   //  9,216 B
    short (*W4s)[72] = (short(*)[72])(smem + 19456);   // 13,824 B
#pragma unroll
    for (int mi = 0; mi < 2; ++mi) {
      int rbase = (mh * 2 + mi) * 16 + quad * 4;  // local row 0..63
      int dbase = m0 + rbase;
#pragma unroll
      for (int ni = 0; ni < NT; ++ni) {
        int f = (nh * NT + ni) * 16 + l16;
        f32x4 a = acc[mi][ni];
#pragma unroll
        for (int reg = 0; reg < 4; ++reg) {
          int d = dbase + reg;
          float v = 0.f;
          if (d < NN)
            v = fmaxf(Yg[(size_t)d * 192 + O1 + f] - Yg[(size_t)d * 192 + O2 + f] +
                      a[reg] + bias[f], 0.f);
          H1s[rbase + reg][f] = f2bf(v);
        }
      }
    }
    for (int i = t; i < 96 * 8; i += 256) {  // 96 rows x 8 short8 groups
      int r = i >> 3, ko = (i & 7) * 8;
      *(short8*)(&W4s[r][ko]) = *(const short8*)(W4bT + r * 64 + ko);
    }
    __syncthreads();
    f32x4 acc2[2][3];
#pragma unroll
    for (int mi = 0; mi < 2; ++mi)
#pragma unroll
      for (int nj = 0; nj < 3; ++nj) acc2[mi][nj] = (f32x4){0.f, 0.f, 0.f, 0.f};
#pragma unroll
    for (int kc = 0; kc < 2; ++kc) {
      short8 a2f[2], b2f[3];
#pragma unroll
      for (int mi = 0; mi < 2; ++mi)
        a2f[mi] = *(const short8*)(&H1s[(mh * 2 + mi) * 16 + l16][kc * 32 + quad * 8]);
#pragma unroll
      for (int nj = 0; nj < 3; ++nj)
        b2f[nj] = *(const short8*)(&W4s[(nh * 3 + nj) * 16 + l16][kc * 32 + quad * 8]);
#pragma unroll
      for (int mi = 0; mi < 2; ++mi)
#pragma unroll
        for (int nj = 0; nj < 3; ++nj)
          acc2[mi][nj] = __builtin_amdgcn_mfma_f32_16x16x32_bf16(a2f[mi], b2f[nj], acc2[mi][nj], 0, 0, 0);
    }
#pragma unroll
    for (int mi = 0; mi < 2; ++mi) {
      int dbase = m0 + (mh * 2 + mi) * 16 + quad * 4;
      if (dbase < NN) {  // dbase % 4 == 0, never straddles 268
#pragma unroll
        for (int nj = 0; nj < 3; ++nj) {
          int c = (nh * 3 + nj) * 16 + l16;  // 0..95
          f32x4 a = acc2[mi][nj];
          int dst = (c < 64) ? c : c + 96;
#pragma unroll
          for (int reg = 0; reg < 4; ++reg)
            Yg[(size_t)(dbase + reg) * 192 + dst] = a[reg];
          if (c >= 64) {
            short4v p;
#pragma unroll
            for (int reg = 0; reg < 4; ++reg) p[reg] = f2bf(a[reg]);
            *(short4v*)(OutB2 + (size_t)(c - 64) * KP + dbase) = p;
          }
        }
      }
    }
    __syncthreads();  // H1s/W4s reads done before next phase reuses smem
  }
}

// ---------------------------------------------------------------------------
// K2: MEGA kernel — gemm1 || L-build || per-graph-pipelined 4-phase cheb.
// Grid 2304 = 640 gemm1 + 1024 build + 640 cheb. Producers (lower blockIdx)
// never wait -> dispatched/retire first; 640 cheb blocks co-resident
// (LDS 40,256 B -> 4 blocks/CU = 1024 slots; __launch_bounds__(256,3) floors
// VGPR residency at 3 blocks/CU = 768 slots) -> spin barriers cannot deadlock.
// Per-graph phase skew: graph g runs its cheb chain as soon as ITS 13
// producer blocks arrive — the 4 formerly-global GEMM stages now pipeline
// across graphs.
// ---------------------------------------------------------------------------
__global__ __launch_bounds__(256, 3) void k_mega(
    const int* __restrict__ ei1, const float* __restrict__ ea1,
    const int* __restrict__ ei2, const float* __restrict__ ea2,
    const float* x1, const float* x2, float* dinv_all,
    const short* WbT, short* Lb, float* Y, short* arena,
    const short* W4bT, const float* b1, const float* b4) {
  __shared__ __align__(16) char smem[40256];
  int t = threadIdx.x;
  int bx = blockIdx.x;
  unsigned* cntA = (unsigned*)dinv_all;  // cnt[g] at float-index g*272+271

  if (bx < 640) {
    // ===================== gemm1 (MFMA) =====================
    int xcd = bx & 7, rest = bx >> 3;       // rest 0..79
    int g = xcd + 8 * (rest / 5);           // graph on XCD g&7
    int m0 = (rest % 5) * 64;
    const float* A32 = (g < 64) ? (x1 + (size_t)g * NN * 268)
                                : (x2 + (size_t)(g - 64) * NN * 268);
    float* Yg = Y + (size_t)g * NN * 192;
    short* Y2tg = arena + (size_t)g * SLAB_S + Y2T_S;
    short (*As)[40] = (short(*)[40])smem;
    short (*Bs)[40] = (short(*)[40])(smem + 5120);
    int w = t >> 6, lane = t & 63;
    int quad = lane >> 4, l16 = lane & 15;
    int mh = w & 1, nh = w >> 1;
    f32x4 acc[2][6];
#pragma unroll
    for (int mi = 0; mi < 2; ++mi)
#pragma unroll
      for (int ni = 0; ni < 6; ++ni) acc[mi][ni] = (f32x4){0.f, 0.f, 0.f, 0.f};

    int sr = t >> 2, sko = (t & 3) * 8;
    for (int k0 = 0; k0 < KP; k0 += 32) {
      {
        int row = m0 + sr;
        int k = k0 + sko;
        float4 va = make_float4(0.f, 0.f, 0.f, 0.f), vb = va;
        if (row < NN && k < 268) va = *(const float4*)(A32 + (size_t)row * 268 + k);
        if (row < NN && k + 4 < 268) vb = *(const float4*)(A32 + (size_t)row * 268 + k + 4);
        short8 s;
        s[0] = f2bf(va.x); s[1] = f2bf(va.y); s[2] = f2bf(va.z); s[3] = f2bf(va.w);
        s[4] = f2bf(vb.x); s[5] = f2bf(vb.y); s[6] = f2bf(vb.z); s[7] = f2bf(vb.w);
        *(short8*)(&As[sr][sko]) = s;
      }
#pragma unroll
      for (int i = 0; i < 3; ++i) {
        int r = sr + i * 64;
        *(short8*)(&Bs[r][sko]) = *(const short8*)(WbT + (size_t)r * KP + k0 + sko);
      }
      __syncthreads();
      short8 af[2], bfr[6];
#pragma unroll
      for (int mi = 0; mi < 2; ++mi)
        af[mi] = *(const short8*)(&As[(mh * 2 + mi) * 16 + l16][quad * 8]);
#pragma unroll
      for (int ni = 0; ni < 6; ++ni)
        bfr[ni] = *(const short8*)(&Bs[(nh * 6 + ni) * 16 + l16][quad * 8]);
#pragma unroll
      for (int mi = 0; mi < 2; ++mi)
#pragma unroll
        for (int ni = 0; ni < 6; ++ni)
          acc[mi][ni] = __builtin_amdgcn_mfma_f32_16x16x32_bf16(af[mi], bfr[ni], acc[mi][ni], 0, 0, 0);
      __syncthreads();
    }
    // C/D: col = lane&15, row = quad*4 + reg
#pragma unroll
    for (int mi = 0; mi < 2; ++mi) {
      int rbase = m0 + (mh * 2 + mi) * 16 + quad * 4;
#pragma unroll
      for (int reg = 0; reg < 4; ++reg) {
        int row = rbase + reg;
        if (row < NN) {
#pragma unroll
          for (int ni = 0; ni < 6; ++ni) {
            int col = (nh * 6 + ni) * 16 + l16;
            Yg[(size_t)row * 192 + col] = acc[mi][ni][reg];
          }
        }
      }
      if (rbase < NN) {  // rbase % 4 == 0, never straddles 268
#pragma unroll
        for (int ni = 0; ni < 6; ++ni) {
          int col = (nh * 6 + ni) * 16 + l16;
          if (col >= 128) {
            short4v p;
#pragma unroll
            for (int reg = 0; reg < 4; ++reg) p[reg] = f2bf(acc[mi][ni][reg]);
            *(short4v*)(Y2tg + (size_t)(col - 128) * KP + rbase) = p;
          }
        }
      }
    }
    graph_arrive(&cntA[(size_t)g * 272 + 271], t);
  } else if (bx < 1664) {
    // ===================== Laplacian build =====================
    int l = bx - 640;                // 0..1023 = 8 xcd * 16 g * 8 tiles
    int xcd = l & 7, rest = l >> 3;  // rest 0..127
    int g = xcd + 8 * (rest & 15);
    int tile = rest >> 4;            // 0..7
    int r0 = tile * 34;
    const int* ei = (g < 64) ? (ei1 + (size_t)g * 2 * NE) : (ei2 + (size_t)(g - 64) * 2 * NE);
    const float* ea = (g < 64) ? (ea1 + (size_t)g * NE) : (ea2 + (size_t)(g - 64) * NE);
    int* LrowI = (int*)smem;                      // 34*288 ints = 39,168 B
    float* dv = (float*)(smem + 39168);           // 272 floats
    for (int i = t; i < 34 * 288; i += 256) LrowI[i] = 0;
    for (int i = t; i < 272; i += 256) dv[i] = dinv_all[(size_t)g * 272 + i];
    __syncthreads();
#pragma unroll 8
    for (int e = t; e < NE; e += 256) {
      int d = ei[NE + e];
      int s = ei[e];
      float w = ea[e];
      if (d >= r0 && d < r0 + 34 && s != d) {
        atomicAdd(&LrowI[(d - r0) * 288 + s],
                  (int)lrintf(-dv[s] * w * dv[d] * 16777216.f));  // native ds_add
      }
    }
    __syncthreads();
    short* Lbg = Lb + (size_t)g * 272 * KP + (size_t)r0 * KP;
    for (int i = t; i < 34 * 288; i += 256)
      Lbg[i] = f2bf((float)LrowI[i] * (1.f / 16777216.f));
    graph_arrive(&cntA[(size_t)g * 272 + 271], t);
  } else {
    // ===================== cheb chain (4 phases, per-graph sync) ============
    int cb = bx - 1664;              // 0..639
    int xcd = cb & 7, idx = cb >> 3; // idx 0..79
    int g = xcd + 8 * (idx / 5);
    int m0 = (idx % 5) * 64;
    unsigned* cnt = &cntA[(size_t)g * 272 + 271];
    const short* Lbg = Lb + (size_t)g * 272 * KP;
    float* Yg = Y + (size_t)g * NN * 192;
    short* slab = arena + (size_t)g * SLAB_S;

    // phase A: Ut = bf16(Y1 + 2*L@Y2)
    graph_wait(cnt, 13, t);
    cheb_phase<64, 0, 64, 0>(Lbg, slab + Y2T_S, Yg, nullptr,
                             slab + UT_S, nullptr, nullptr, m0, t, smem);
    graph_arrive(cnt, t);
    // phase B: H1=relu(Y0-Y2+L@Ut+b1) in LDS; Yb = H1@W4 -> Y + Yb2t
    graph_wait(cnt, 18, t);
    cheb_phase<64, 3, 0, 128>(Lbg, slab + UT_S, Yg, b1,
                              nullptr, W4bT, slab + YB2T_S, m0, t, smem);
    graph_arrive(cnt, t);
    // phase C: U2t = bf16(Yb1 + 2*L@Yb2)
    graph_wait(cnt, 23, t);
    cheb_phase<32, 0, 32, 0>(Lbg, slab + YB2T_S, Yg, nullptr,
                             slab + U2T_S, nullptr, nullptr, m0, t, smem);
    graph_arrive(cnt, t);
    // phase D: H2 = relu(Yb0 - Yb2 + L@U2 + b4)  (cls reads via launch order)
    graph_wait(cnt, 28, t);
    cheb_phase<32, 2, 0, 160>(Lbg, slab + U2T_S, Yg, b4,
                              slab + H2_S, nullptr, nullptr, m0, t, smem);
  }
}

// ---------------------------------------------------------------------------
// K3: fused classifier. Per block: 64 rows (2 graphs x 32) of H2 read from the
// per-graph arenas. L1: MFMA 64x112 (K=288) -> Z1=relu(.+bc1) in LDS.
// L2: Z2=relu(Z1@Wc2+bc2) register-tiled. L3: out = Z2 . Wc3 + bc3.
// ---------------------------------------------------------------------------
__global__ __launch_bounds__(256) void k_cls(
    const short* __restrict__ arena, const short* __restrict__ Wc1bT,
    const float* __restrict__ bc1, const float* __restrict__ Wc2,
    const float* __restrict__ bc2, const float* __restrict__ Wc3,
    const float* __restrict__ bc3, float* __restrict__ out) {
  int m0 = blockIdx.x * 64;
  __shared__ __align__(16) short As[64][40];
  __shared__ __align__(16) short Bs[112][40];
  __shared__ __align__(16) float Z1s[64][116];
  __shared__ __align__(16) float W2s[100][64];
  __shared__ __align__(16) float Z2s[64][64];
  __shared__ float w3s[64];
  int t = threadIdx.x;
  int w = t >> 6, lane = t & 63;
  int quad = lane >> 4, l16 = lane & 15;
  f32x4 acc[7];
#pragma unroll
  for (int ni = 0; ni < 7; ++ni) acc[ni] = (f32x4){0.f, 0.f, 0.f, 0.f};

  int sr = t >> 2, sko = (t & 3) * 8;
  int r = m0 + sr;  // global H2 row -> graph r>>5, feature r&31
  const short* h2row = arena + (size_t)(r >> 5) * SLAB_S + H2_S + (size_t)(r & 31) * KP;
  for (int k0 = 0; k0 < KP; k0 += 32) {
    *(short8*)(&As[sr][sko]) = *(const short8*)(h2row + k0 + sko);
#pragma unroll
    for (int i = 0; i < 2; ++i) {
      int idx = t + i * 256;
      if (idx < 112 * 4) {
        int rr = idx >> 2, ko = (idx & 3) * 8;
        *(short8*)(&Bs[rr][ko]) = *(const short8*)(Wc1bT + (size_t)rr * KP + k0 + ko);
      }
    }
    __syncthreads();
    short8 af = *(const short8*)(&As[w * 16 + l16][quad * 8]);
#pragma unroll
    for (int ni = 0; ni < 7; ++ni) {
      short8 bfr = *(const short8*)(&Bs[ni * 16 + l16][quad * 8]);
      acc[ni] = __builtin_amdgcn_mfma_f32_16x16x32_bf16(af, bfr, acc[ni], 0, 0, 0);
    }
    __syncthreads();
  }
#pragma unroll
  for (int ni = 0; ni < 7; ++ni) {
    int col = ni * 16 + l16;
    if (col < 100) {
      float b = bc1[col];
#pragma unroll
      for (int reg = 0; reg < 4; ++reg) {
        int wrow = w * 16 + quad * 4 + reg;
        Z1s[wrow][col] = fmaxf(acc[ni][reg] + b, 0.f);
      }
    }
  }
  for (int i = t; i < 100 * 64; i += 256) {
    int rr = i >> 6, c = i & 63;
    W2s[rr][c] = (c < 60) ? Wc2[(size_t)rr * 60 + c] : 0.f;
  }
  if (t < 64) w3s[t] = (t < 60) ? Wc3[t] : 0.f;
  __syncthreads();
  {
    int r2 = (t >> 3) * 2;
    int c8 = (t & 7) * 8;
    float a2[2][8];
#pragma unroll
    for (int i = 0; i < 2; ++i)
#pragma unroll
      for (int j = 0; j < 8; ++j) a2[i][j] = 0.f;
#pragma unroll 4
    for (int k = 0; k < 100; ++k) {
      float x0 = Z1s[r2][k], x1 = Z1s[r2 + 1][k];
      float4 wA = *(const float4*)(&W2s[k][c8]);
      float4 wB = *(const float4*)(&W2s[k][c8 + 4]);
      float wv[8] = {wA.x, wA.y, wA.z, wA.w, wB.x, wB.y, wB.z, wB.w};
#pragma unroll
      for (int j = 0; j < 8; ++j) { a2[0][j] += x0 * wv[j]; a2[1][j] += x1 * wv[j]; }
    }
#pragma unroll
    for (int j = 0; j < 8; ++j) {
      int c = c8 + j;
      float bb = (c < 60) ? bc2[c] : 0.f;
      Z2s[r2][c] = fmaxf(a2[0][j] + bb, 0.f);
      Z2s[r2 + 1][c] = fmaxf(a2[1][j] + bb, 0.f);
    }
  }
  __syncthreads();
  if (t < 64) {
    float acc3 = bc3[0];
#pragma unroll
    for (int k = 0; k < 60; ++k) acc3 += Z2s[t][k] * w3s[k];
    out[m0 + t] = acc3;
  }
}

extern "C" void kernel_launch(void* const* d_in, const int* in_sizes, int n_in,
                              void* d_out, int out_size, void* d_ws, size_t ws_size,
                              hipStream_t stream) {
  (void)in_sizes; (void)n_in; (void)out_size; (void)ws_size;
  const float* x1  = (const float*)d_in[0];
  const int*   ei1 = (const int*)d_in[1];
  const float* ea1 = (const float*)d_in[2];
  const float* x2  = (const float*)d_in[3];
  const int*   ei2 = (const int*)d_in[4];
  const float* ea2 = (const float*)d_in[5];
  const float* W1  = (const float*)d_in[6];
  const float* b1  = (const float*)d_in[7];
  const float* W4  = (const float*)d_in[8];
  const float* b4  = (const float*)d_in[9];
  const float* Wc1 = (const float*)d_in[10];
  const float* bc1 = (const float*)d_in[11];
  const float* Wc2 = (const float*)d_in[12];
  const float* bc2 = (const float*)d_in[13];
  const float* Wc3 = (const float*)d_in[14];
  const float* bc3 = (const float*)d_in[15];

  char* ws = (char*)d_ws;
  float* dinv  = (float*)(ws + OFF_DINV);
  short* arena = (short*)(ws + OFF_ARENA);
  short* WbT   = (short*)(ws + OFF_WBT);
  short* Wc1bT = (short*)(ws + OFF_WC1BT);
  short* Lb    = (short*)(ws + OFF_LB);
  float* Y     = (float*)(ws + OFF_Y);
  short* W4bT  = (short*)(ws + OFF_W4BT);
  float* out   = (float*)d_out;

  // prep: per-graph degree->dinv (also zeroes per-graph counters) + weights
  k_prep<<<494, 256, 0, stream>>>(ei1, ea1, ei2, ea2, W1, Wc1, W4,
                                  WbT, Wc1bT, W4bT, dinv);
  // mega: gemm1 || L-build || per-graph-pipelined 4-phase cheb chain
  k_mega<<<2304, 256, 0, stream>>>(ei1, ea1, ei2, ea2, x1, x2, dinv,
                                   WbT, Lb, Y, arena, W4bT, b1, b4);
  // fused classifier
  k_cls<<<64, 256, 0, stream>>>(arena, Wc1bT, bc1, Wc2, bc2, Wc3, bc3, out);
}

// Round 3
// 274.649 us; speedup vs baseline: 1.2300x; 1.2300x over previous
//
#include <hip/hip_runtime.h>
#include <hip/hip_bf16.h>

#define NN 268
#define NE 8192
#define KP 288   // padded node dim (268 -> 288)
#define K2 576   // 2*KP: concatenated [L | LL] contraction

typedef short short8 __attribute__((ext_vector_type(8)));   // 8 bf16 = 4 VGPR
typedef short short4v __attribute__((ext_vector_type(4)));  // 4 bf16 = 8B
typedef float f32x4 __attribute__((ext_vector_type(4)));

__device__ __forceinline__ short f2bf(float f) {
  __hip_bfloat16 h = __float2bfloat16(f);
  return *reinterpret_cast<short*>(&h);
}

// ---------------------------------------------------------------------------
// Workspace (bytes). Peak 100,740,096 (pool is 256 MiB per harness fills).
//   OFF_ARENA per-graph slab, 110,592 B x 128 = 14,155,776
//     slab(sh)+    0: Bt1 bf16[64][576] = [Y1t | 2*Y2t]   (gemm1 out, beta in)
//     slab(sh)+36864: Bt2 bf16[32][576] = [Yb1t | 2*Yb2t] (beta out, gamma in)
//     slab(sh)+    0: H2  bf16[32][288] (gamma out, cls in; overlays dead Bt1)
//   OFF_WC1BT Wc1bT bf16[112][288]      64,512
//   OFF_W4BT  W4bT  bf16[96][64]        12,288
//   OFF_LB    Lb    bf16[128][272][288] 20,054,016   (rows d, cols s)
//   OFF_LBT   LbT   bf16[128][272][288] 20,054,016   (rows s, cols d)
//   OFF_LLB   LLb   bf16[128][272][288] 20,054,016   (LL = L @ L, row-major)
//   OFF_Y     Y     f32 [128][268][192] 26,345,472
//   All cross-stage overlays ordered by LAUNCH boundaries (no intra-kernel
//   cross-graph sync — round-2's agent-scope fences killed L2 locality).
// ---------------------------------------------------------------------------
#define OFF_ARENA 0
#define SLAB_S    55296     // slab stride in SHORTS (110,592 B)
#define BT1_S     0
#define BT2_S     36864
#define H2_S      0
#define OFF_WC1BT 14155776
#define OFF_W4BT  14220288
#define OFF_LB    14232576
#define OFF_LBT   34286592
#define OFF_LLB   54340608
#define OFF_Y     74394624

// ---------------------------------------------------------------------------
// K1: one fused launch, 2838 blocks, three independent families (no
// intra-launch consumption):
//  [0,640):    gemm1  Y[g] = X[g] @ [W1_0|W1_1|W1_2] (M=268,K=268,N=192), MFMA.
//              B staged straight from fp32 W1 (LDS transpose-scatter), fp32 Y
//              out for cols {0-64,128-192}, and Bt1 = [Y1t | 2*Y2t] bf16.
//              Register prefetch of next k-step's A and B global loads.
//  [640,2688): Laplacian build, 34-row tiles. fam0 -> Lb rows d; fam1 -> LbT
//              rows s (same math: L[d][s] = -dinv[s]*w*dinv[d], symmetric in
//              the dinv factors). Each block self-computes degree/dinv in LDS
//              (edges are L2-resident; kills the separate prep dependency).
//  [2688,2838): weight conversion tail: Wc1bT (cls), W4bT (beta).
// ---------------------------------------------------------------------------
__global__ __launch_bounds__(256) void k_fused(
    const int* __restrict__ ei1, const float* __restrict__ ea1,
    const int* __restrict__ ei2, const float* __restrict__ ea2,
    const float* __restrict__ x1, const float* __restrict__ x2,
    const float* __restrict__ W1, const float* __restrict__ Wc1,
    const float* __restrict__ W4,
    short* __restrict__ Lb, short* __restrict__ LbT,
    float* __restrict__ Y, short* __restrict__ arena,
    short* __restrict__ Wc1bT, short* __restrict__ W4bT) {
  __shared__ __align__(16) char smem[40448];
  int t = threadIdx.x;
  int bx = blockIdx.x;

  if (bx < 640) {
    // ===================== gemm1 (MFMA) =====================
    int xcd = bx & 7, rest = bx >> 3;       // rest 0..79
    int g = xcd + 8 * (rest / 5);           // graph on XCD g&7
    int m0 = (rest % 5) * 64;
    const float* A32 = (g < 64) ? (x1 + (size_t)g * NN * 268)
                                : (x2 + (size_t)(g - 64) * NN * 268);
    float* Yg = Y + (size_t)g * NN * 192;
    short* Bt1g = arena + (size_t)g * SLAB_S + BT1_S;
    short (*As)[40] = (short(*)[40])smem;                  //  5,120 B
    short (*Bs)[40] = (short(*)[40])(smem + 5120);         // 15,360 B
    int w = t >> 6, lane = t & 63;
    int quad = lane >> 4, l16 = lane & 15;
    int mh = w & 1, nh = w >> 1;
    f32x4 acc[2][6];
#pragma unroll
    for (int mi = 0; mi < 2; ++mi)
#pragma unroll
      for (int ni = 0; ni < 6; ++ni) acc[mi][ni] = (f32x4){0.f, 0.f, 0.f, 0.f};

    int sr = t >> 2, sko = (t & 3) * 8;
    float4 pva, pvb, pb0[3], pb1[3];
    auto loadA = [&](int K0) {
      int row = m0 + sr, k = K0 + sko;  // k multiple of 8 -> k<268 => k+3<=267
      pva = make_float4(0.f, 0.f, 0.f, 0.f); pvb = pva;
      if (row < NN && k < 268) pva = *(const float4*)(A32 + (size_t)row * 268 + k);
      if (row < NN && k + 4 < 268) pvb = *(const float4*)(A32 + (size_t)row * 268 + k + 4);
    };
    auto loadB = [&](int K0) {
      // 768 units: uid -> (kp 0..15 k-pair, ng 0..47 n-quad). W1 [3][268][64].
#pragma unroll
      for (int u = 0; u < 3; ++u) {
        int uid = t + u * 256;
        int kp = uid & 15, n0 = (uid >> 4) * 4;
        int kb = n0 >> 6, j0 = n0 & 63;
        int k = K0 + kp * 2;
        pb0[u] = (k < 268) ? *(const float4*)(W1 + ((size_t)kb * 268 + k) * 64 + j0)
                           : make_float4(0.f, 0.f, 0.f, 0.f);
        pb1[u] = (k + 1 < 268) ? *(const float4*)(W1 + ((size_t)kb * 268 + k + 1) * 64 + j0)
                               : make_float4(0.f, 0.f, 0.f, 0.f);
      }
    };
    loadA(0); loadB(0);
    for (int k0 = 0; k0 < KP; k0 += 32) {
      {
        short8 s;
        const float* fa = (const float*)&pva;
        const float* fb = (const float*)&pvb;
#pragma unroll
        for (int j = 0; j < 4; ++j) { s[j] = f2bf(fa[j]); s[4 + j] = f2bf(fb[j]); }
        *(short8*)(&As[sr][sko]) = s;
      }
#pragma unroll
      for (int u = 0; u < 3; ++u) {
        int uid = t + u * 256;
        int kp = uid & 15, n0 = (uid >> 4) * 4;
        const float* f0 = (const float*)&pb0[u];
        const float* f1 = (const float*)&pb1[u];
#pragma unroll
        for (int jj = 0; jj < 4; ++jj) {
          unsigned lo = (unsigned short)f2bf(f0[jj]);
          unsigned hi = (unsigned short)f2bf(f1[jj]);
          *(unsigned*)(&Bs[n0 + jj][kp * 2]) = lo | (hi << 16);
        }
      }
      __syncthreads();
      if (k0 + 32 < KP) { loadA(k0 + 32); loadB(k0 + 32); }  // hides under MFMA
      short8 af[2], bfr[6];
#pragma unroll
      for (int mi = 0; mi < 2; ++mi)
        af[mi] = *(const short8*)(&As[(mh * 2 + mi) * 16 + l16][quad * 8]);
#pragma unroll
      for (int ni = 0; ni < 6; ++ni)
        bfr[ni] = *(const short8*)(&Bs[(nh * 6 + ni) * 16 + l16][quad * 8]);
#pragma unroll
      for (int mi = 0; mi < 2; ++mi)
#pragma unroll
        for (int ni = 0; ni < 6; ++ni)
          acc[mi][ni] = __builtin_amdgcn_mfma_f32_16x16x32_bf16(af[mi], bfr[ni], acc[mi][ni], 0, 0, 0);
      __syncthreads();
    }
    // C/D: col = lane&15, row = quad*4 + reg
#pragma unroll
    for (int mi = 0; mi < 2; ++mi) {
      int rbase = m0 + (mh * 2 + mi) * 16 + quad * 4;
#pragma unroll
      for (int reg = 0; reg < 4; ++reg) {
        int row = rbase + reg;
        if (row < NN) {
#pragma unroll
          for (int ni = 0; ni < 6; ++ni) {
            int col = (nh * 6 + ni) * 16 + l16;
            if (col < 64 || col >= 128)  // Y1 fp32 never consumed
              Yg[(size_t)row * 192 + col] = acc[mi][ni][reg];
          }
        }
      }
      if (rbase < NN) {  // rbase % 4 == 0, never straddles 268
#pragma unroll
        for (int ni = 0; ni < 6; ++ni) {
          int col = (nh * 6 + ni) * 16 + l16;
          if (col >= 64 && col < 128) {        // Y1t -> Bt1 part0
            short4v p;
#pragma unroll
            for (int reg = 0; reg < 4; ++reg) p[reg] = f2bf(acc[mi][ni][reg]);
            *(short4v*)(Bt1g + (size_t)(col - 64) * K2 + rbase) = p;
          } else if (col >= 128) {             // 2*Y2t -> Bt1 part1
            short4v p;
#pragma unroll
            for (int reg = 0; reg < 4; ++reg) p[reg] = f2bf(2.f * acc[mi][ni][reg]);
            *(short4v*)(Bt1g + (size_t)(col - 128) * K2 + KP + rbase) = p;
          }
        }
      }
    }
    if (m0 == 256) {  // zero Bt1 node-pad cols 268..287 in both halves
      for (int i = t; i < 64 * 40; i += 256) {
        int f = i / 40, j = i - f * 40;
        Bt1g[(size_t)f * K2 + (j < 20 ? 268 + j : KP + 268 + (j - 20))] = 0;
      }
    }
  } else if (bx < 2688) {
    // ===================== Laplacian build (L and L^T families) ============
    int bb = bx - 640;
    int fam = bb >> 10;              // 0: Lb rows d; 1: LbT rows s
    int l = bb & 1023;               // 8 xcd * 16 g * 8 tiles
    int xcd = l & 7, rest = l >> 3;
    int g = xcd + 8 * (rest & 15);
    int tile = rest >> 4;
    int r0 = tile * 34;
    const int* ei = (g < 64) ? (ei1 + (size_t)g * 2 * NE) : (ei2 + (size_t)(g - 64) * 2 * NE);
    const float* ea = (g < 64) ? (ea1 + (size_t)g * NE) : (ea2 + (size_t)(g - 64) * NE);
    int* LrowI = (int*)smem;                      // 34*288 ints = 39,168 B
    float* dv = (float*)(smem + 39168);           // 272 f32 (unions with degU)
    unsigned* degU = (unsigned*)dv;
    for (int i = t; i < 34 * 288; i += 256) LrowI[i] = 0;
    for (int i = t; i < 272; i += 256) degU[i] = 0u;
    __syncthreads();
#pragma unroll 4
    for (int e = t; e < NE; e += 256) {           // pass 1: degree
      int s = ei[e], d = ei[NE + e];
      float wv = ea[e];
      if (s != d) atomicAdd(&degU[s], (unsigned)lrintf(wv * 1048576.f));
    }
    __syncthreads();
    for (int i = t; i < 272; i += 256) {          // in-place deg -> dinv
      unsigned v = degU[i];
      dv[i] = v ? rsqrtf((float)v * (1.f / 1048576.f)) : 0.f;
    }
    __syncthreads();
#pragma unroll 8
    for (int e = t; e < NE; e += 256) {           // pass 2: tile accumulate
      int s = ei[e], d = ei[NE + e];
      float wv = ea[e];
      int a = fam ? s : d, c = fam ? d : s;
      if (a >= r0 && a < r0 + 34 && s != d) {
        atomicAdd(&LrowI[(a - r0) * 288 + c],
                  (int)lrintf(-dv[s] * wv * dv[d] * 16777216.f));  // native ds_add
      }
    }
    __syncthreads();
    short* dst = (fam ? LbT : Lb) + (size_t)g * 272 * KP + (size_t)r0 * KP;
    for (int i = t; i < 34 * 288; i += 256)
      dst[i] = f2bf((float)LrowI[i] * (1.f / 16777216.f));
  } else {
    // ===================== weight conversion tail ==========================
    int idx = (bx - 2688) * 256 + t;  // 0..38399
    if (idx < 112 * KP) {
      int n = idx / KP, k = idx - n * KP;
      float v = (n < 100 && k < 268) ? Wc1[(size_t)k * 100 + n] : 0.f;
      Wc1bT[idx] = f2bf(v);
    } else {
      int i4 = idx - 112 * KP;       // 0..6143
      int n = i4 >> 6, k = i4 & 63;  // n in [0,96), k in [0,64)
      W4bT[i4] = f2bf(W4[(((size_t)(n >> 5)) * 64 + k) * 32 + (n & 31)]);
    }
  }
}

// ---------------------------------------------------------------------------
// K2: LL = Lb @ LbT^T per graph (row-major out, M=272 pad 64-tiles, N=288,
// K=288). B rows are LbT rows (contiguous). Rows >=272 of LbT are never
// written -> B-load guard zeroes them, so LLb cols 272-287 come out 0 (and
// cols/rows 268-271 are 0 because L's pad rows/cols are 0). 640 blocks.
// ---------------------------------------------------------------------------
__global__ __launch_bounds__(256) void k_LL(
    const short* __restrict__ Lb, const short* __restrict__ LbT,
    short* __restrict__ LLb) {
  int l = blockIdx.x;
  int xcd = l & 7, idx = l >> 3;
  int g = xcd + 8 * (idx / 5);
  int m0 = (idx % 5) * 64;
  const short* Ag = Lb + (size_t)g * 272 * KP;
  const short* Bg = LbT + (size_t)g * 272 * KP;
  short* Cg = LLb + (size_t)g * 272 * KP;
  __shared__ __align__(16) short As[64][40];    //  5,120 B
  __shared__ __align__(16) short Bs[288][40];   // 23,040 B
  int t = threadIdx.x;
  int w = t >> 6, lane = t & 63;
  int quad = lane >> 4, l16 = lane & 15;
  int mh = w & 1, nh = w >> 1;
  f32x4 acc[2][9];
#pragma unroll
  for (int mi = 0; mi < 2; ++mi)
#pragma unroll
    for (int ni = 0; ni < 9; ++ni) acc[mi][ni] = (f32x4){0.f, 0.f, 0.f, 0.f};

  int sr = t >> 2, sko = (t & 3) * 8;
  short8 z8 = {0, 0, 0, 0, 0, 0, 0, 0};
  short8 pA, pB[5];
  auto loadAB = [&](int K0) {
    int ar = m0 + sr;
    pA = (ar < 272) ? *(const short8*)(Ag + (size_t)ar * KP + K0 + sko) : z8;
#pragma unroll
    for (int i = 0; i < 4; ++i)
      pB[i] = *(const short8*)(Bg + (size_t)(sr + i * 64) * KP + K0 + sko);
    if (sr < 32)
      pB[4] = (256 + sr < 272) ? *(const short8*)(Bg + (size_t)(256 + sr) * KP + K0 + sko) : z8;
  };
  loadAB(0);
  for (int k0 = 0; k0 < KP; k0 += 32) {
    *(short8*)(&As[sr][sko]) = pA;
#pragma unroll
    for (int i = 0; i < 4; ++i) *(short8*)(&Bs[sr + i * 64][sko]) = pB[i];
    if (sr < 32) *(short8*)(&Bs[256 + sr][sko]) = pB[4];
    __syncthreads();
    if (k0 + 32 < KP) loadAB(k0 + 32);   // prefetch hides under MFMA
    short8 af[2], bfr[9];
#pragma unroll
    for (int mi = 0; mi < 2; ++mi)
      af[mi] = *(const short8*)(&As[(mh * 2 + mi) * 16 + l16][quad * 8]);
#pragma unroll
    for (int ni = 0; ni < 9; ++ni)
      bfr[ni] = *(const short8*)(&Bs[nh * 144 + ni * 16 + l16][quad * 8]);
#pragma unroll
    for (int mi = 0; mi < 2; ++mi)
#pragma unroll
      for (int ni = 0; ni < 9; ++ni)
        acc[mi][ni] = __builtin_amdgcn_mfma_f32_16x16x32_bf16(af[mi], bfr[ni], acc[mi][ni], 0, 0, 0);
    __syncthreads();
  }
#pragma unroll
  for (int mi = 0; mi < 2; ++mi) {
    int rbase = m0 + (mh * 2 + mi) * 16 + quad * 4;
    if (rbase < 272) {  // rbase%4==0 -> all 4 rows < 272
#pragma unroll
      for (int reg = 0; reg < 4; ++reg) {
        int row = rbase + reg;
#pragma unroll
        for (int ni = 0; ni < 9; ++ni) {
          int col = nh * 144 + ni * 16 + l16;
          Cg[(size_t)row * KP + col] = f2bf(acc[mi][ni][reg]);
        }
      }
    }
  }
}

// ---------------------------------------------------------------------------
// K3/K4: single-shot cheb layer. C = [Lb | LLb] @ Bt^T  (K=576).
// MODE 1 (beta, NCOLS=64): H1 = relu(Y0 - Y2 + C + b1) -> LDS bf16; fused
//   H1 @ W4bT (M=64,N=96,K=64): c<32 -> Y[d][c] (Yb0 fp32); 32<=c<64 ->
//   Bt2 part0 (Yb1t); c>=64 -> Y[d][c+96] (Yb2 fp32) + Bt2 part1 (2*Yb2t).
// MODE 2 (gamma, NCOLS=32): H2 = relu(Yb0 - Yb2 + C + b4) -> OutS[f][d]
//   (+ node-pad zero rows 268..287 via the m0==256 block).
// 640 blocks each, same XCD swizzle as everything else.
// ---------------------------------------------------------------------------
template <int NCOLS, int MODE>
__global__ __launch_bounds__(256) void k_cheb(
    const short* __restrict__ Lb, const short* __restrict__ LLb,
    const short* __restrict__ BtBase, float* __restrict__ Y,
    const float* __restrict__ bias, short* __restrict__ OutBase,
    const short* __restrict__ W4bT) {
  int l = blockIdx.x;
  int xcd = l & 7, idx = l >> 3;
  int g = xcd + 8 * (idx / 5);
  int m0 = (idx % 5) * 64;
  const short* Ag0 = Lb + (size_t)g * 272 * KP;
  const short* Ag1 = LLb + (size_t)g * 272 * KP;
  const short* Btg = BtBase + (size_t)g * SLAB_S;
  short* OutS = OutBase + (size_t)g * SLAB_S;
  float* Yg = Y + (size_t)g * NN * 192;
  __shared__ __align__(16) short As[64][40];
  __shared__ __align__(16) short Bs[NCOLS][40];
  int t = threadIdx.x;
  int w = t >> 6, lane = t & 63;
  int quad = lane >> 4, l16 = lane & 15;
  constexpr int NT = NCOLS / 32;
  int mh = w & 1, nh = w >> 1;
  f32x4 acc[2][NT];
#pragma unroll
  for (int mi = 0; mi < 2; ++mi)
#pragma unroll
    for (int ni = 0; ni < NT; ++ni) acc[mi][ni] = (f32x4){0.f, 0.f, 0.f, 0.f};

  int sr = t >> 2, sko = (t & 3) * 8;
  short8 z8 = {0, 0, 0, 0, 0, 0, 0, 0};
  short8 pA, pB;
  auto loadAB = [&](int K0) {
    const short* Ab = (K0 < KP) ? Ag0 : Ag1;
    int kk = (K0 < KP) ? K0 : K0 - KP;
    int ar = m0 + sr;
    pA = (ar < 272) ? *(const short8*)(Ab + (size_t)ar * KP + kk + sko) : z8;
    if (sr < NCOLS) pB = *(const short8*)(Btg + (size_t)sr * K2 + K0 + sko);
  };
  loadAB(0);
  for (int k0 = 0; k0 < K2; k0 += 32) {
    *(short8*)(&As[sr][sko]) = pA;
    if (sr < NCOLS) *(short8*)(&Bs[sr][sko]) = pB;
    __syncthreads();
    if (k0 + 32 < K2) loadAB(k0 + 32);   // prefetch hides under MFMA
    short8 af[2], bfr[NT];
#pragma unroll
    for (int mi = 0; mi < 2; ++mi)
      af[mi] = *(const short8*)(&As[(mh * 2 + mi) * 16 + l16][quad * 8]);
#pragma unroll
    for (int ni = 0; ni < NT; ++ni)
      bfr[ni] = *(const short8*)(&Bs[(nh * NT + ni) * 16 + l16][quad * 8]);
#pragma unroll
    for (int mi = 0; mi < 2; ++mi)
#pragma unroll
      for (int ni = 0; ni < NT; ++ni)
        acc[mi][ni] = __builtin_amdgcn_mfma_f32_16x16x32_bf16(af[mi], bfr[ni], acc[mi][ni], 0, 0, 0);
    __syncthreads();
  }

  if constexpr (MODE == 2) {
#pragma unroll
    for (int mi = 0; mi < 2; ++mi) {
      int dbase = m0 + (mh * 2 + mi) * 16 + quad * 4;
      if (dbase < NN) {  // dbase % 4 == 0, never straddles 268
#pragma unroll
        for (int ni = 0; ni < NT; ++ni) {
          int f = (nh * NT + ni) * 16 + l16;
          f32x4 a = acc[mi][ni];
          short4v p;
#pragma unroll
          for (int reg = 0; reg < 4; ++reg) {
            int d = dbase + reg;
            float v = Yg[(size_t)d * 192 + f] - Yg[(size_t)d * 192 + 160 + f] +
                      a[reg] + bias[f];
            p[reg] = f2bf(fmaxf(v, 0.f));
          }
          *(short4v*)(OutS + (size_t)f * KP + dbase) = p;
        }
      }
    }
    if (m0 == 256) {  // zero node-pad 268..287 of H2 rows
      for (int i = t; i < 32 * 20; i += 256) {
        int f = i / 20, d = 268 + (i - f * 20);
        OutS[(size_t)f * KP + d] = 0;
      }
    }
  } else {
    // MODE 1: H1 -> LDS bf16 -> fused MFMA @ W4bT
    __shared__ __align__(16) short H1s[64][72];
    __shared__ __align__(16) short W4s[96][72];
#pragma unroll
    for (int mi = 0; mi < 2; ++mi) {
      int rbase = (mh * 2 + mi) * 16 + quad * 4;  // local row 0..63
      int dbase = m0 + rbase;
#pragma unroll
      for (int ni = 0; ni < NT; ++ni) {
        int f = (nh * NT + ni) * 16 + l16;
        f32x4 a = acc[mi][ni];
#pragma unroll
        for (int reg = 0; reg < 4; ++reg) {
          int d = dbase + reg;
          float v = 0.f;
          if (d < NN)
            v = fmaxf(Yg[(size_t)d * 192 + f] - Yg[(size_t)d * 192 + 128 + f] +
                      a[reg] + bias[f], 0.f);
          H1s[rbase + reg][f] = f2bf(v);
        }
      }
    }
    for (int i = t; i < 96 * 8; i += 256) {
      int r = i >> 3, ko = (i & 7) * 8;
      *(short8*)(&W4s[r][ko]) = *(const short8*)(W4bT + r * 64 + ko);
    }
    __syncthreads();
    f32x4 acc2[2][3];
#pragma unroll
    for (int mi = 0; mi < 2; ++mi)
#pragma unroll
      for (int nj = 0; nj < 3; ++nj) acc2[mi][nj] = (f32x4){0.f, 0.f, 0.f, 0.f};
#pragma unroll
    for (int kc = 0; kc < 2; ++kc) {
      short8 a2f[2], b2f[3];
#pragma unroll
      for (int mi = 0; mi < 2; ++mi)
        a2f[mi] = *(const short8*)(&H1s[(mh * 2 + mi) * 16 + l16][kc * 32 + quad * 8]);
#pragma unroll
      for (int nj = 0; nj < 3; ++nj)
        b2f[nj] = *(const short8*)(&W4s[(nh * 3 + nj) * 16 + l16][kc * 32 + quad * 8]);
#pragma unroll
      for (int mi = 0; mi < 2; ++mi)
#pragma unroll
        for (int nj = 0; nj < 3; ++nj)
          acc2[mi][nj] = __builtin_amdgcn_mfma_f32_16x16x32_bf16(a2f[mi], b2f[nj], acc2[mi][nj], 0, 0, 0);
    }
#pragma unroll
    for (int mi = 0; mi < 2; ++mi) {
      int dbase = m0 + (mh * 2 + mi) * 16 + quad * 4;
      if (dbase < NN) {  // dbase % 4 == 0, never straddles 268
#pragma unroll
        for (int nj = 0; nj < 3; ++nj) {
          int c = (nh * 3 + nj) * 16 + l16;  // 0..95
          f32x4 a = acc2[mi][nj];
          if (c < 32) {                       // Yb0 fp32
#pragma unroll
            for (int reg = 0; reg < 4; ++reg)
              Yg[(size_t)(dbase + reg) * 192 + c] = a[reg];
          } else if (c < 64) {                // Yb1t -> Bt2 part0
            short4v p;
#pragma unroll
            for (int reg = 0; reg < 4; ++reg) p[reg] = f2bf(a[reg]);
            *(short4v*)(OutS + (size_t)(c - 32) * K2 + dbase) = p;
          } else {                            // Yb2 fp32 + 2*Yb2t -> part1
            short4v p;
#pragma unroll
            for (int reg = 0; reg < 4; ++reg) {
              Yg[(size_t)(dbase + reg) * 192 + c + 96] = a[reg];
              p[reg] = f2bf(2.f * a[reg]);
            }
            *(short4v*)(OutS + (size_t)(c - 64) * K2 + KP + dbase) = p;
          }
        }
      }
    }
    if (m0 == 256) {  // zero Bt2 node-pad cols 268..287 in both halves
      for (int i = t; i < 32 * 40; i += 256) {
        int f = i / 40, j = i - f * 40;
        OutS[(size_t)f * K2 + (j < 20 ? 268 + j : KP + 268 + (j - 20))] = 0;
      }
    }
  }
}

// ---------------------------------------------------------------------------
// K5: fused classifier. Per block: 64 rows (2 graphs x 32) of H2 from arenas.
// L1: MFMA 64x112 (K=288) -> Z1=relu(.+bc1) in LDS. L2: register-tiled.
// L3: out = Z2 . Wc3 + bc3.
// ---------------------------------------------------------------------------
__global__ __launch_bounds__(256) void k_cls(
    const short* __restrict__ arena, const short* __restrict__ Wc1bT,
    const float* __restrict__ bc1, const float* __restrict__ Wc2,
    const float* __restrict__ bc2, const float* __restrict__ Wc3,
    const float* __restrict__ bc3, float* __restrict__ out) {
  int m0 = blockIdx.x * 64;
  __shared__ __align__(16) short As[64][40];
  __shared__ __align__(16) short Bs[112][40];
  __shared__ __align__(16) float Z1s[64][116];
  __shared__ __align__(16) float W2s[100][64];
  __shared__ __align__(16) float Z2s[64][64];
  __shared__ float w3s[64];
  int t = threadIdx.x;
  int w = t >> 6, lane = t & 63;
  int quad = lane >> 4, l16 = lane & 15;
  f32x4 acc[7];
#pragma unroll
  for (int ni = 0; ni < 7; ++ni) acc[ni] = (f32x4){0.f, 0.f, 0.f, 0.f};

  int sr = t >> 2, sko = (t & 3) * 8;
  int r = m0 + sr;  // H2 row -> graph r>>5, feature r&31
  const short* h2row = arena + (size_t)(r >> 5) * SLAB_S + H2_S + (size_t)(r & 31) * KP;
  for (int k0 = 0; k0 < KP; k0 += 32) {
    *(short8*)(&As[sr][sko]) = *(const short8*)(h2row + k0 + sko);
#pragma unroll
    for (int i = 0; i < 2; ++i) {
      int idx = t + i * 256;
      if (idx < 112 * 4) {
        int rr = idx >> 2, ko = (idx & 3) * 8;
        *(short8*)(&Bs[rr][ko]) = *(const short8*)(Wc1bT + (size_t)rr * KP + k0 + ko);
      }
    }
    __syncthreads();
    short8 af = *(const short8*)(&As[w * 16 + l16][quad * 8]);
#pragma unroll
    for (int ni = 0; ni < 7; ++ni) {
      short8 bfr = *(const short8*)(&Bs[ni * 16 + l16][quad * 8]);
      acc[ni] = __builtin_amdgcn_mfma_f32_16x16x32_bf16(af, bfr, acc[ni], 0, 0, 0);
    }
    __syncthreads();
  }
#pragma unroll
  for (int ni = 0; ni < 7; ++ni) {
    int col = ni * 16 + l16;
    if (col < 100) {
      float b = bc1[col];
#pragma unroll
      for (int reg = 0; reg < 4; ++reg) {
        int wrow = w * 16 + quad * 4 + reg;
        Z1s[wrow][col] = fmaxf(acc[ni][reg] + b, 0.f);
      }
    }
  }
  for (int i = t; i < 100 * 64; i += 256) {
    int rr = i >> 6, c = i & 63;
    W2s[rr][c] = (c < 60) ? Wc2[(size_t)rr * 60 + c] : 0.f;
  }
  if (t < 64) w3s[t] = (t < 60) ? Wc3[t] : 0.f;
  __syncthreads();
  {
    int r2 = (t >> 3) * 2;
    int c8 = (t & 7) * 8;
    float a2[2][8];
#pragma unroll
    for (int i = 0; i < 2; ++i)
#pragma unroll
      for (int j = 0; j < 8; ++j) a2[i][j] = 0.f;
#pragma unroll 4
    for (int k = 0; k < 100; ++k) {
      float x0 = Z1s[r2][k], x1 = Z1s[r2 + 1][k];
      float4 wA = *(const float4*)(&W2s[k][c8]);
      float4 wB = *(const float4*)(&W2s[k][c8 + 4]);
      float wv[8] = {wA.x, wA.y, wA.z, wA.w, wB.x, wB.y, wB.z, wB.w};
#pragma unroll
      for (int j = 0; j < 8; ++j) { a2[0][j] += x0 * wv[j]; a2[1][j] += x1 * wv[j]; }
    }
#pragma unroll
    for (int j = 0; j < 8; ++j) {
      int c = c8 + j;
      float bb = (c < 60) ? bc2[c] : 0.f;
      Z2s[r2][c] = fmaxf(a2[0][j] + bb, 0.f);
      Z2s[r2 + 1][c] = fmaxf(a2[1][j] + bb, 0.f);
    }
  }
  __syncthreads();
  if (t < 64) {
    float acc3 = bc3[0];
#pragma unroll
    for (int k = 0; k < 60; ++k) acc3 += Z2s[t][k] * w3s[k];
    out[m0 + t] = acc3;
  }
}

extern "C" void kernel_launch(void* const* d_in, const int* in_sizes, int n_in,
                              void* d_out, int out_size, void* d_ws, size_t ws_size,
                              hipStream_t stream) {
  (void)in_sizes; (void)n_in; (void)out_size; (void)ws_size;
  const float* x1  = (const float*)d_in[0];
  const int*   ei1 = (const int*)d_in[1];
  const float* ea1 = (const float*)d_in[2];
  const float* x2  = (const float*)d_in[3];
  const int*   ei2 = (const int*)d_in[4];
  const float* ea2 = (const float*)d_in[5];
  const float* W1  = (const float*)d_in[6];
  const float* b1  = (const float*)d_in[7];
  const float* W4  = (const float*)d_in[8];
  const float* b4  = (const float*)d_in[9];
  const float* Wc1 = (const float*)d_in[10];
  const float* bc1 = (const float*)d_in[11];
  const float* Wc2 = (const float*)d_in[12];
  const float* bc2 = (const float*)d_in[13];
  const float* Wc3 = (const float*)d_in[14];
  const float* bc3 = (const float*)d_in[15];

  char* ws = (char*)d_ws;
  short* arena = (short*)(ws + OFF_ARENA);
  short* Wc1bT = (short*)(ws + OFF_WC1BT);
  short* W4bT  = (short*)(ws + OFF_W4BT);
  short* Lb    = (short*)(ws + OFF_LB);
  short* LbT   = (short*)(ws + OFF_LBT);
  short* LLb   = (short*)(ws + OFF_LLB);
  float* Y     = (float*)(ws + OFF_Y);
  float* out   = (float*)d_out;

  // K1: gemm1 || L/L^T build (self-contained degree) || weight conversions
  k_fused<<<2838, 256, 0, stream>>>(ei1, ea1, ei2, ea2, x1, x2, W1, Wc1, W4,
                                    Lb, LbT, Y, arena, Wc1bT, W4bT);
  // K2: LL = L @ L (row-major bf16)
  k_LL<<<640, 256, 0, stream>>>(Lb, LbT, LLb);
  // K3: cheb layer 1 in ONE GEMM (K=576) + fused @W4 -> Yb + Bt2
  k_cheb<64, 1><<<640, 256, 0, stream>>>(Lb, LLb, arena + BT1_S, Y, b1,
                                         arena + BT2_S, W4bT);
  // K4: cheb layer 2 in ONE GEMM (K=576) -> H2
  k_cheb<32, 2><<<640, 256, 0, stream>>>(Lb, LLb, arena + BT2_S, Y, b4,
                                         arena + H2_S, nullptr);
  // K5: fused classifier
  k_cls<<<64, 256, 0, stream>>>(arena, Wc1bT, bc1, Wc2, bc2, Wc3, bc3, out);
}

// Round 4
// 234.714 us; speedup vs baseline: 1.4392x; 1.1701x over previous
//
#include <hip/hip_runtime.h>
#include <hip/hip_bf16.h>

#define NN 268
#define NE 8192
#define KP 288   // padded node dim (268 -> 288)

typedef short short8 __attribute__((ext_vector_type(8)));   // 8 bf16 = 4 VGPR
typedef short short4v __attribute__((ext_vector_type(4)));  // 4 bf16 = 8B
typedef float f32x4 __attribute__((ext_vector_type(4)));

__device__ __forceinline__ short f2bf(float f) {
  __hip_bfloat16 h = __float2bfloat16(f);
  return *reinterpret_cast<short*>(&h);
}

// ---------------------------------------------------------------------------
// Workspace (bytes). Peak 51,444,736.
//   OFF_DINV  dinv  f32 [128][272]           139,264
//   OFF_ARENA Y2t   bf16[128][64][288]     4,718,592  (gemm1 out, mega in)
//   OFF_WBT   WbT   bf16[192][288]           110,592
//   OFF_WC1BT Wc1bT bf16[112][288]            64,512
//   OFF_W4BT  W4bT  bf16[96][64]              12,288
//   OFF_LB    Lb    bf16[128][272][288]   20,054,016
//   OFF_Y     Y     f32 [128][268][192]   26,345,472
// Math chain is BIT-IDENTICAL to the round-1 passed kernel; only the
// execution structure changed (per-graph mega-block, LDS-resident state).
// ---------------------------------------------------------------------------
#define OFF_DINV  0
#define OFF_ARENA 139264
#define ARENA_SLAB_S 18432   // shorts per graph: Y2t [64][288]
#define OFF_WBT   4857856
#define OFF_WC1BT 4968448
#define OFF_W4BT  5032960
#define OFF_LB    5045248
#define OFF_Y     25099264

// ---------------------------------------------------------------------------
// K1: fused prep (round-1 verbatim). 494 blocks.
//   blocks [0,128):   per-graph degree in LDS -> dinv.
//   blocks [128,494): weight conversions (WbT, Wc1bT, W4bT).
// ---------------------------------------------------------------------------
__global__ __launch_bounds__(256) void k_prep(
    const int* __restrict__ ei1, const float* __restrict__ ea1,
    const int* __restrict__ ei2, const float* __restrict__ ea2,
    const float* __restrict__ W1, const float* __restrict__ Wc1,
    const float* __restrict__ W4, short* __restrict__ WbT,
    short* __restrict__ Wc1bT, short* __restrict__ W4bT,
    float* __restrict__ dinv) {
  int t = threadIdx.x;
  int b = blockIdx.x;
  if (b < 128) {
    int g = b;
    const int* ei = (g < 64) ? (ei1 + (size_t)g * 2 * NE) : (ei2 + (size_t)(g - 64) * 2 * NE);
    const float* ea = (g < 64) ? (ea1 + (size_t)g * NE) : (ea2 + (size_t)(g - 64) * NE);
    __shared__ unsigned degL[NN];
    for (int n = t; n < NN; n += 256) degL[n] = 0u;
    __syncthreads();
#pragma unroll 4
    for (int e = t; e < NE; e += 256) {
      int s = ei[e], d = ei[NE + e];
      float w = ea[e];
      if (s != d) atomicAdd(&degL[s], (unsigned)lrintf(w * 1048576.f));
    }
    __syncthreads();
    for (int n = t; n < 272; n += 256) {
      float r = 0.f;
      if (n < NN) {
        unsigned v = degL[n];
        if (v) r = rsqrtf((float)v * (1.f / 1048576.f));
      }
      dinv[(size_t)g * 272 + n] = r;
    }
  } else {
    int idx = (b - 128) * 256 + t;  // 0..93695
    if (idx < 192 * KP) {
      int n = idx / KP, kp = idx - n * KP;
      int kb = n >> 6, j = n & 63;
      float v = (kp < 268) ? W1[((size_t)kb * 268 + kp) * 64 + j] : 0.f;
      WbT[idx] = f2bf(v);
    } else if (idx < 192 * KP + 112 * KP) {
      int i2 = idx - 192 * KP;  // 0..32255
      int n = i2 / KP, k = i2 - n * KP;
      float v = (n < 100 && k < 268) ? Wc1[(size_t)k * 100 + n] : 0.f;
      Wc1bT[i2] = f2bf(v);
    } else {
      int i4 = idx - (192 * KP + 112 * KP);  // 0..6143
      int n = i4 >> 6, k = i4 & 63;          // n in [0,96), k in [0,64)
      W4bT[i4] = f2bf(W4[(((size_t)(n >> 5)) * 64 + k) * 32 + (n & 31)]);
    }
  }
}

// ---------------------------------------------------------------------------
// K2: fused Laplacian build + gemm1 (round-1 verbatim; measured 48 us).
// blocks [0,640): gemm1 (MFMA), Y fp32 out + Y2t bf16 transposed out.
// blocks [640,1664): dense Laplacian 34-row tiles (reads dinv from prep).
// ---------------------------------------------------------------------------
__global__ __launch_bounds__(256) void k_build_gemm1(
    const int* __restrict__ ei1, const float* __restrict__ ea1,
    const int* __restrict__ ei2, const float* __restrict__ ea2,
    const float* __restrict__ dinv_all, short* __restrict__ Lb,
    const float* __restrict__ x1, const float* __restrict__ x2,
    const short* __restrict__ WbT, float* __restrict__ Y,
    short* __restrict__ Y2t) {
  __shared__ __align__(16) char smem[34 * 288 * 4 + 272 * 4];  // 40,256 B
  int t = threadIdx.x;
  int bx = blockIdx.x;
  if (bx < 640) {
    // ===================== gemm1 (MFMA) =====================
    int xcd = bx & 7, rest = bx >> 3;       // rest 0..79
    int g = xcd + 8 * (rest / 5);           // graph on XCD g&7
    int m0 = (rest % 5) * 64;
    const float* A32 = (g < 64) ? (x1 + (size_t)g * NN * 268)
                                : (x2 + (size_t)(g - 64) * NN * 268);
    float* Yg = Y + (size_t)g * NN * 192;
    short* Y2tg = Y2t + (size_t)g * ARENA_SLAB_S;
    short (*As)[40] = (short(*)[40])smem;                     //  5,120 B
    short (*Bs)[40] = (short(*)[40])(smem + 64 * 40 * 2);     // 15,360 B
    int w = t >> 6, lane = t & 63;
    int quad = lane >> 4, l16 = lane & 15;
    int mh = w & 1, nh = w >> 1;
    f32x4 acc[2][6];
#pragma unroll
    for (int mi = 0; mi < 2; ++mi)
#pragma unroll
      for (int ni = 0; ni < 6; ++ni) acc[mi][ni] = (f32x4){0.f, 0.f, 0.f, 0.f};

    int sr = t >> 2, sko = (t & 3) * 8;
    for (int k0 = 0; k0 < KP; k0 += 32) {
      {
        int row = m0 + sr;
        int k = k0 + sko;
        float4 va = make_float4(0.f, 0.f, 0.f, 0.f), vb = va;
        if (row < NN && k < 268) va = *(const float4*)(A32 + (size_t)row * 268 + k);
        if (row < NN && k + 4 < 268) vb = *(const float4*)(A32 + (size_t)row * 268 + k + 4);
        short8 s;
        s[0] = f2bf(va.x); s[1] = f2bf(va.y); s[2] = f2bf(va.z); s[3] = f2bf(va.w);
        s[4] = f2bf(vb.x); s[5] = f2bf(vb.y); s[6] = f2bf(vb.z); s[7] = f2bf(vb.w);
        *(short8*)(&As[sr][sko]) = s;
      }
#pragma unroll
      for (int i = 0; i < 3; ++i) {
        int r = sr + i * 64;
        *(short8*)(&Bs[r][sko]) = *(const short8*)(WbT + (size_t)r * KP + k0 + sko);
      }
      __syncthreads();
      short8 af[2], bfr[6];
#pragma unroll
      for (int mi = 0; mi < 2; ++mi)
        af[mi] = *(const short8*)(&As[(mh * 2 + mi) * 16 + l16][quad * 8]);
#pragma unroll
      for (int ni = 0; ni < 6; ++ni)
        bfr[ni] = *(const short8*)(&Bs[(nh * 6 + ni) * 16 + l16][quad * 8]);
#pragma unroll
      for (int mi = 0; mi < 2; ++mi)
#pragma unroll
        for (int ni = 0; ni < 6; ++ni)
          acc[mi][ni] = __builtin_amdgcn_mfma_f32_16x16x32_bf16(af[mi], bfr[ni], acc[mi][ni], 0, 0, 0);
      __syncthreads();
    }
    // C/D: col = lane&15, row = quad*4 + reg
#pragma unroll
    for (int mi = 0; mi < 2; ++mi) {
      int rbase = m0 + (mh * 2 + mi) * 16 + quad * 4;
#pragma unroll
      for (int reg = 0; reg < 4; ++reg) {
        int row = rbase + reg;
        if (row < NN) {
#pragma unroll
          for (int ni = 0; ni < 6; ++ni) {
            int col = (nh * 6 + ni) * 16 + l16;
            Yg[(size_t)row * 192 + col] = acc[mi][ni][reg];
          }
        }
      }
      if (rbase < NN) {  // rbase % 4 == 0, never straddles 268
#pragma unroll
        for (int ni = 0; ni < 6; ++ni) {
          int col = (nh * 6 + ni) * 16 + l16;
          if (col >= 128) {
            short4v p;
#pragma unroll
            for (int reg = 0; reg < 4; ++reg) p[reg] = f2bf(acc[mi][ni][reg]);
            *(short4v*)(Y2tg + (size_t)(col - 128) * KP + rbase) = p;
          }
        }
      }
    }
  } else {
    // ===================== Laplacian build =====================
    int l = bx - 640;                // 0..1023 = 8 xcd * 16 g * 8 tiles
    int xcd = l & 7, rest = l >> 3;  // rest 0..127
    int g = xcd + 8 * (rest & 15);
    int tile = rest >> 4;            // 0..7
    int r0 = tile * 34;
    const int* ei = (g < 64) ? (ei1 + (size_t)g * 2 * NE) : (ei2 + (size_t)(g - 64) * 2 * NE);
    const float* ea = (g < 64) ? (ea1 + (size_t)g * NE) : (ea2 + (size_t)(g - 64) * NE);
    int* LrowI = (int*)smem;                      // 34*288 ints = 39,168 B
    float* dv = (float*)(smem + 39168);           // 272 floats
    for (int i = t; i < 34 * 288; i += 256) LrowI[i] = 0;
    for (int i = t; i < 272; i += 256) dv[i] = dinv_all[(size_t)g * 272 + i];
    __syncthreads();
#pragma unroll 8
    for (int e = t; e < NE; e += 256) {
      int d = ei[NE + e];
      int s = ei[e];
      float w = ea[e];
      if (d >= r0 && d < r0 + 34 && s != d) {
        atomicAdd(&LrowI[(d - r0) * 288 + s],
                  (int)lrintf(-dv[s] * w * dv[d] * 16777216.f));  // native ds_add
      }
    }
    __syncthreads();
    short* Lbg = Lb + (size_t)g * 272 * KP + (size_t)r0 * KP;
    for (int i = t; i < 34 * 288; i += 256)
      Lbg[i] = f2bf((float)LrowI[i] * (1.f / 16777216.f));
  }
}

// ---------------------------------------------------------------------------
// K3: MEGA — the entire post-gemm1 chain for one graph in ONE block.
// 128 blocks (one per graph, XCD g%8 matches build's L placement), 256 thr,
// 111,616 B LDS -> 1 block/CU. Phases separated by __syncthreads only:
//   P0 copy Y2t->LDS            P1 Ut   = bf16(Y1 + 2*L@Y2)     [LDS]
//   P2 H1   = relu(Y0-Y2+L@Ut+b1) [LDS]   P3 Yb = H1@W4 -> Yg f32 + Yb2t LDS
//   P4 Ut2  = bf16(Yb1 + 2*L@Yb2) [LDS]   P5 H2 = relu(Yb0-Yb2+L@Ut2+b4)
//   P6 classifier (MFMA L1 + reg-tiled L2 + dot L3) -> out
// L-apply k-loops have NO barriers: A-frags read per-lane from global Lb
// (L2-resident), B-frags read from LDS (row stride SP=296 shorts: 148 dwords
// %32 = 20 -> conflict-free b128 reads; 288 would be 8-way).
// Residual adds read Y f32 from global exactly as round-1's dgemm epilogues.
// ---------------------------------------------------------------------------
#define SP 296
#define YT2_O  0
#define H1N_O  0
#define UT_O   40960
#define UT2_O  40960
#define H2T_O  59904
#define W4S_O  78848
#define YBT_O  92672
#define Z1_O   0
#define W2S_O  14848
#define Z2_O   78848
#define W3S_O  87040
#define SM_SZ  111616

template <int NT4>
__device__ __forceinline__ void cheb_mm(const short* __restrict__ Lbg,
                                        const short* __restrict__ B0,
                                        int mt, int l16, int quad,
                                        f32x4* acc) {
  const short* Arow = Lbg + (size_t)(mt * 16 + l16) * KP + quad * 8;
#pragma unroll
  for (int k = 0; k < 9; ++k) {
    short8 af = *(const short8*)(Arow + k * 32);
#pragma unroll
    for (int nt = 0; nt < NT4; ++nt) {
      short8 bf = *(const short8*)(B0 + (size_t)(nt * 16 + l16) * SP + k * 32 + quad * 8);
      acc[nt] = __builtin_amdgcn_mfma_f32_16x16x32_bf16(af, bf, acc[nt], 0, 0, 0);
    }
  }
}

__global__ __launch_bounds__(256, 1) void k_mega(
    const short* __restrict__ Lb, const short* __restrict__ arena,
    float* __restrict__ Y, const short* __restrict__ W4bT,
    const short* __restrict__ Wc1bT,
    const float* __restrict__ b1, const float* __restrict__ b4,
    const float* __restrict__ bc1, const float* __restrict__ Wc2,
    const float* __restrict__ bc2, const float* __restrict__ Wc3,
    const float* __restrict__ bc3, float* __restrict__ out) {
  __shared__ __align__(16) char sm[SM_SZ];
  int g = blockIdx.x;
  int t = threadIdx.x;
  int w = t >> 6, lane = t & 63;
  int quad = lane >> 4, l16 = lane & 15;
  const short* Lbg = Lb + (size_t)g * 272 * KP;
  const short* Y2tg = arena + (size_t)g * ARENA_SLAB_S;
  float* Yg = Y + (size_t)g * NN * 192;

  // ---- P0: Y2t -> LDS [64][SP]; cols >=268 forced to 0 (poison-safe) ----
  for (int i = t; i < 64 * 37; i += 256) {
    int r = i / 37, c = (i - r * 37) * 8;
    short8 v = {0, 0, 0, 0, 0, 0, 0, 0};
    if (c < 264) {
      v = *(const short8*)(Y2tg + (size_t)r * KP + c);
    } else if (c == 264) {
      v = *(const short8*)(Y2tg + (size_t)r * KP + 264);
      v[4] = 0; v[5] = 0; v[6] = 0; v[7] = 0;
    }
    *(short8*)(sm + YT2_O + ((size_t)r * SP + c) * 2) = v;
  }
  __syncthreads();

  // ---- P1: Ut[f][d] = bf16(Y1[d][f] + 2*(L@Y2)[d][f]) ----
  for (int i = t; i < 64 * 20; i += 256) {  // zero node-pad cols 268..287
    int f = i / 20, d = 268 + (i - f * 20);
    *(short*)(sm + UT_O + ((size_t)f * SP + d) * 2) = 0;
  }
  for (int mt = w; mt < 17; mt += 4) {
    f32x4 acc[4];
#pragma unroll
    for (int nt = 0; nt < 4; ++nt) acc[nt] = (f32x4){0.f, 0.f, 0.f, 0.f};
    cheb_mm<4>(Lbg, (const short*)(sm + YT2_O), mt, l16, quad, acc);
    int dbase = mt * 16 + quad * 4;
    if (dbase < NN) {
#pragma unroll
      for (int nt = 0; nt < 4; ++nt) {
        int f = nt * 16 + l16;
        short4v p;
#pragma unroll
        for (int reg = 0; reg < 4; ++reg)
          p[reg] = f2bf(Yg[(size_t)(dbase + reg) * 192 + 64 + f] + 2.f * acc[nt][reg]);
        *(short4v*)(sm + UT_O + ((size_t)f * SP + dbase) * 2) = p;
      }
    }
  }
  __syncthreads();

  // ---- P2: H1n[d][f] = relu(Y0 - Y2 + (L@Ut)[d][f] + b1[f]), stride 72 ----
  for (int mt = w; mt < 17; mt += 4) {
    f32x4 acc[4];
#pragma unroll
    for (int nt = 0; nt < 4; ++nt) acc[nt] = (f32x4){0.f, 0.f, 0.f, 0.f};
    cheb_mm<4>(Lbg, (const short*)(sm + UT_O), mt, l16, quad, acc);
    int dbase = mt * 16 + quad * 4;
    if (dbase < NN) {
#pragma unroll
      for (int nt = 0; nt < 4; ++nt) {
        int f = nt * 16 + l16;
        float bb = b1[f];
#pragma unroll
        for (int reg = 0; reg < 4; ++reg) {
          int d = dbase + reg;
          float v = Yg[(size_t)d * 192 + f] - Yg[(size_t)d * 192 + 128 + f] +
                    acc[nt][reg] + bb;
          *(short*)(sm + H1N_O + ((size_t)d * 72 + f) * 2) = f2bf(fmaxf(v, 0.f));
        }
      }
    }
  }
  __syncthreads();

  // ---- P3: Yb^T[c][d] = (H1 @ W4)[d][c]; c<64 -> Yg[d][c] f32,
  //          c>=64 -> Yg[d][c+96] f32 + YBT (Yb2t bf16) ----
  for (int i = t; i < 96 * 8; i += 256) {   // stage W4s [96][72]
    int r = i >> 3, ko = (i & 7) * 8;
    *(short8*)(sm + W4S_O + ((size_t)r * 72 + ko) * 2) =
        *(const short8*)(W4bT + r * 64 + ko);
  }
  for (int i = t; i < 32 * 20; i += 256) {  // zero YBT node-pads
    int f = i / 20, d = 268 + (i - f * 20);
    *(short*)(sm + YBT_O + ((size_t)f * SP + d) * 2) = 0;
  }
  __syncthreads();
  for (int id = w; id < 102; id += 4) {     // 6 c-tiles x 17 d-tiles
    int mt = id / 17, nt = id - mt * 17;
    f32x4 a1 = (f32x4){0.f, 0.f, 0.f, 0.f};
#pragma unroll
    for (int kc = 0; kc < 2; ++kc) {
      short8 af = *(const short8*)(sm + W4S_O +
          ((size_t)(mt * 16 + l16) * 72 + kc * 32 + quad * 8) * 2);
      short8 bf = *(const short8*)(sm + H1N_O +
          ((size_t)(nt * 16 + l16) * 72 + kc * 32 + quad * 8) * 2);
      a1 = __builtin_amdgcn_mfma_f32_16x16x32_bf16(af, bf, a1, 0, 0, 0);
    }
    int d = nt * 16 + l16;
    if (d < NN) {
      int c0 = mt * 16 + quad * 4;
#pragma unroll
      for (int reg = 0; reg < 4; ++reg) {
        int c = c0 + reg;
        float a = a1[reg];
        Yg[(size_t)d * 192 + ((c < 64) ? c : c + 96)] = a;
        if (c >= 64)
          *(short*)(sm + YBT_O + ((size_t)(c - 64) * SP + d) * 2) = f2bf(a);
      }
    }
  }
  __syncthreads();

  // ---- P4: Ut2[f][d] = bf16(Yb1[d][f] + 2*(L@Yb2)[d][f]) ----
  for (int i = t; i < 32 * 20; i += 256) {
    int f = i / 20, d = 268 + (i - f * 20);
    *(short*)(sm + UT2_O + ((size_t)f * SP + d) * 2) = 0;
  }
  for (int mt = w; mt < 17; mt += 4) {
    f32x4 acc[2];
#pragma unroll
    for (int nt = 0; nt < 2; ++nt) acc[nt] = (f32x4){0.f, 0.f, 0.f, 0.f};
    cheb_mm<2>(Lbg, (const short*)(sm + YBT_O), mt, l16, quad, acc);
    int dbase = mt * 16 + quad * 4;
    if (dbase < NN) {
#pragma unroll
      for (int nt = 0; nt < 2; ++nt) {
        int f = nt * 16 + l16;
        short4v p;
#pragma unroll
        for (int reg = 0; reg < 4; ++reg)
          p[reg] = f2bf(Yg[(size_t)(dbase + reg) * 192 + 32 + f] + 2.f * acc[nt][reg]);
        *(short4v*)(sm + UT2_O + ((size_t)f * SP + dbase) * 2) = p;
      }
    }
  }
  __syncthreads();

  // ---- P5: H2T[f][d] = relu(Yb0 - Yb2 + (L@Ut2)[d][f] + b4[f]) ----
  for (int i = t; i < 32 * 20; i += 256) {
    int f = i / 20, d = 268 + (i - f * 20);
    *(short*)(sm + H2T_O + ((size_t)f * SP + d) * 2) = 0;
  }
  for (int mt = w; mt < 17; mt += 4) {
    f32x4 acc[2];
#pragma unroll
    for (int nt = 0; nt < 2; ++nt) acc[nt] = (f32x4){0.f, 0.f, 0.f, 0.f};
    cheb_mm<2>(Lbg, (const short*)(sm + UT2_O), mt, l16, quad, acc);
    int dbase = mt * 16 + quad * 4;
    if (dbase < NN) {
#pragma unroll
      for (int nt = 0; nt < 2; ++nt) {
        int f = nt * 16 + l16;
        float bb = b4[f];
        short4v p;
#pragma unroll
        for (int reg = 0; reg < 4; ++reg) {
          int d = dbase + reg;
          float v = Yg[(size_t)d * 192 + f] - Yg[(size_t)d * 192 + 160 + f] +
                    acc[nt][reg] + bb;
          p[reg] = f2bf(fmaxf(v, 0.f));
        }
        *(short4v*)(sm + H2T_O + ((size_t)f * SP + dbase) * 2) = p;
      }
    }
  }
  __syncthreads();

  // ---- P6: classifier. L1: MFMA 32x112 K=288 (A=H2T LDS, B=Wc1bT global) ----
  for (int id = w; id < 14; id += 4) {      // 2 m-tiles x 7 n-tiles
    int mt = id & 1, nt = id >> 1;
    f32x4 a1 = (f32x4){0.f, 0.f, 0.f, 0.f};
#pragma unroll
    for (int k = 0; k < 9; ++k) {
      short8 af = *(const short8*)(sm + H2T_O +
          ((size_t)(mt * 16 + l16) * SP + k * 32 + quad * 8) * 2);
      short8 bf = *(const short8*)(Wc1bT + (size_t)(nt * 16 + l16) * KP + k * 32 + quad * 8);
      a1 = __builtin_amdgcn_mfma_f32_16x16x32_bf16(af, bf, a1, 0, 0, 0);
    }
    int col = nt * 16 + l16;
    if (col < 100) {
      float bb = bc1[col];
      int r0 = mt * 16 + quad * 4;
#pragma unroll
      for (int reg = 0; reg < 4; ++reg)
        *(float*)(sm + Z1_O + ((size_t)(r0 + reg) * 116 + col) * 4) =
            fmaxf(a1[reg] + bb, 0.f);
    }
  }
  for (int i = t; i < 100 * 64; i += 256) {  // stage W2s [100][64]
    int rr = i >> 6, c = i & 63;
    *(float*)(sm + W2S_O + ((size_t)rr * 64 + c) * 4) =
        (c < 60) ? Wc2[(size_t)rr * 60 + c] : 0.f;
  }
  if (t < 64) *(float*)(sm + W3S_O + (size_t)t * 4) = (t < 60) ? Wc3[t] : 0.f;
  __syncthreads();
  if (t < 128) {                             // L2: Z2 = relu(Z1@Wc2+bc2)
    int r2 = (t >> 3) * 2;
    int c8 = (t & 7) * 8;
    float a2[2][8];
#pragma unroll
    for (int i = 0; i < 2; ++i)
#pragma unroll
      for (int j = 0; j < 8; ++j) a2[i][j] = 0.f;
    const float* Z1p = (const float*)(sm + Z1_O);
    const float* W2p = (const float*)(sm + W2S_O);
#pragma unroll 4
    for (int k = 0; k < 100; ++k) {
      float x0 = Z1p[(size_t)r2 * 116 + k], x1 = Z1p[(size_t)(r2 + 1) * 116 + k];
      float4 wA = *(const float4*)(W2p + (size_t)k * 64 + c8);
      float4 wB = *(const float4*)(W2p + (size_t)k * 64 + c8 + 4);
      float wv[8] = {wA.x, wA.y, wA.z, wA.w, wB.x, wB.y, wB.z, wB.w};
#pragma unroll
      for (int j = 0; j < 8; ++j) { a2[0][j] += x0 * wv[j]; a2[1][j] += x1 * wv[j]; }
    }
    float* Z2p = (float*)(sm + Z2_O);
#pragma unroll
    for (int j = 0; j < 8; ++j) {
      int c = c8 + j;
      float bb = (c < 60) ? bc2[c] : 0.f;
      Z2p[(size_t)r2 * 64 + c] = fmaxf(a2[0][j] + bb, 0.f);
      Z2p[(size_t)(r2 + 1) * 64 + c] = fmaxf(a2[1][j] + bb, 0.f);
    }
  }
  __syncthreads();
  if (t < 32) {                              // L3: out = Z2 . Wc3 + bc3
    const float* Z2p = (const float*)(sm + Z2_O);
    const float* w3p = (const float*)(sm + W3S_O);
    float acc3 = bc3[0];
#pragma unroll
    for (int k = 0; k < 60; ++k) acc3 += Z2p[(size_t)t * 64 + k] * w3p[k];
    out[(size_t)g * 32 + t] = acc3;
  }
}

extern "C" void kernel_launch(void* const* d_in, const int* in_sizes, int n_in,
                              void* d_out, int out_size, void* d_ws, size_t ws_size,
                              hipStream_t stream) {
  (void)in_sizes; (void)n_in; (void)out_size; (void)ws_size;
  const float* x1  = (const float*)d_in[0];
  const int*   ei1 = (const int*)d_in[1];
  const float* ea1 = (const float*)d_in[2];
  const float* x2  = (const float*)d_in[3];
  const int*   ei2 = (const int*)d_in[4];
  const float* ea2 = (const float*)d_in[5];
  const float* W1  = (const float*)d_in[6];
  const float* b1  = (const float*)d_in[7];
  const float* W4  = (const float*)d_in[8];
  const float* b4  = (const float*)d_in[9];
  const float* Wc1 = (const float*)d_in[10];
  const float* bc1 = (const float*)d_in[11];
  const float* Wc2 = (const float*)d_in[12];
  const float* bc2 = (const float*)d_in[13];
  const float* Wc3 = (const float*)d_in[14];
  const float* bc3 = (const float*)d_in[15];

  char* ws = (char*)d_ws;
  float* dinv  = (float*)(ws + OFF_DINV);
  short* arena = (short*)(ws + OFF_ARENA);
  short* WbT   = (short*)(ws + OFF_WBT);
  short* Wc1bT = (short*)(ws + OFF_WC1BT);
  short* W4bT  = (short*)(ws + OFF_W4BT);
  short* Lb    = (short*)(ws + OFF_LB);
  float* Y     = (float*)(ws + OFF_Y);
  float* out   = (float*)d_out;

  // L1: dinv + weight conversions (round-1 verbatim)
  k_prep<<<494, 256, 0, stream>>>(ei1, ea1, ei2, ea2, W1, Wc1, W4,
                                  WbT, Wc1bT, W4bT, dinv);
  // L2: dense Laplacian build || gemm1 (round-1 verbatim, measured 48 us)
  k_build_gemm1<<<1664, 256, 0, stream>>>(ei1, ea1, ei2, ea2, dinv, Lb,
                                          x1, x2, WbT, Y, arena);
  // L3: per-graph mega-block — whole cheb chain + classifier, LDS-resident
  k_mega<<<128, 256, 0, stream>>>(Lb, arena, Y, W4bT, Wc1bT,
                                  b1, b4, bc1, Wc2, bc2, Wc3, bc3, out);
}

// Round 5
// 208.990 us; speedup vs baseline: 1.6164x; 1.1231x over previous
//
#include <hip/hip_runtime.h>
#include <hip/hip_bf16.h>

#define NN 268
#define NE 8192
#define KP 288   // padded node dim (268 -> 288)

typedef short short8 __attribute__((ext_vector_type(8)));   // 8 bf16 = 4 VGPR
typedef short short4v __attribute__((ext_vector_type(4)));  // 4 bf16 = 8B
typedef float f32x4 __attribute__((ext_vector_type(4)));

__device__ __forceinline__ short f2bf(float f) {
  __hip_bfloat16 h = __float2bfloat16(f);
  return *reinterpret_cast<short*>(&h);
}

// ---------------------------------------------------------------------------
// Workspace (bytes). Peak 51,444,736.
//   OFF_DINV  dinv  f32 [128][272]           139,264
//   OFF_ARENA Y2t   bf16[128][64][288]     4,718,592  (gemm1 out, mega in)
//   OFF_WBT   WbT   bf16[192][288]           110,592
//   OFF_WC1BT Wc1bT bf16[112][288]            64,512
//   OFF_W4BT  W4bT  bf16[96][64]              12,288
//   OFF_LB    Lb    bf16[128][272][288]   20,054,016
//   OFF_Y     Y     f32 [128][268][192]   26,345,472
// Math chain BIT-IDENTICAL to the round-1 passed kernel. Round-5 change is
// k_mega execution only: 512 threads + reg-prefetch (latency hiding).
// ---------------------------------------------------------------------------
#define OFF_DINV  0
#define OFF_ARENA 139264
#define ARENA_SLAB_S 18432   // shorts per graph: Y2t [64][288]
#define OFF_WBT   4857856
#define OFF_WC1BT 4968448
#define OFF_W4BT  5032960
#define OFF_LB    5045248
#define OFF_Y     25099264

// ---------------------------------------------------------------------------
// K1: fused prep (round-1 verbatim). 494 blocks.
// ---------------------------------------------------------------------------
__global__ __launch_bounds__(256) void k_prep(
    const int* __restrict__ ei1, const float* __restrict__ ea1,
    const int* __restrict__ ei2, const float* __restrict__ ea2,
    const float* __restrict__ W1, const float* __restrict__ Wc1,
    const float* __restrict__ W4, short* __restrict__ WbT,
    short* __restrict__ Wc1bT, short* __restrict__ W4bT,
    float* __restrict__ dinv) {
  int t = threadIdx.x;
  int b = blockIdx.x;
  if (b < 128) {
    int g = b;
    const int* ei = (g < 64) ? (ei1 + (size_t)g * 2 * NE) : (ei2 + (size_t)(g - 64) * 2 * NE);
    const float* ea = (g < 64) ? (ea1 + (size_t)g * NE) : (ea2 + (size_t)(g - 64) * NE);
    __shared__ unsigned degL[NN];
    for (int n = t; n < NN; n += 256) degL[n] = 0u;
    __syncthreads();
#pragma unroll 4
    for (int e = t; e < NE; e += 256) {
      int s = ei[e], d = ei[NE + e];
      float w = ea[e];
      if (s != d) atomicAdd(&degL[s], (unsigned)lrintf(w * 1048576.f));
    }
    __syncthreads();
    for (int n = t; n < 272; n += 256) {
      float r = 0.f;
      if (n < NN) {
        unsigned v = degL[n];
        if (v) r = rsqrtf((float)v * (1.f / 1048576.f));
      }
      dinv[(size_t)g * 272 + n] = r;
    }
  } else {
    int idx = (b - 128) * 256 + t;  // 0..93695
    if (idx < 192 * KP) {
      int n = idx / KP, kp = idx - n * KP;
      int kb = n >> 6, j = n & 63;
      float v = (kp < 268) ? W1[((size_t)kb * 268 + kp) * 64 + j] : 0.f;
      WbT[idx] = f2bf(v);
    } else if (idx < 192 * KP + 112 * KP) {
      int i2 = idx - 192 * KP;  // 0..32255
      int n = i2 / KP, k = i2 - n * KP;
      float v = (n < 100 && k < 268) ? Wc1[(size_t)k * 100 + n] : 0.f;
      Wc1bT[i2] = f2bf(v);
    } else {
      int i4 = idx - (192 * KP + 112 * KP);  // 0..6143
      int n = i4 >> 6, k = i4 & 63;          // n in [0,96), k in [0,64)
      W4bT[i4] = f2bf(W4[(((size_t)(n >> 5)) * 64 + k) * 32 + (n & 31)]);
    }
  }
}

// ---------------------------------------------------------------------------
// K2: fused Laplacian build + gemm1 (round-1 verbatim; measured 48 us).
// ---------------------------------------------------------------------------
__global__ __launch_bounds__(256) void k_build_gemm1(
    const int* __restrict__ ei1, const float* __restrict__ ea1,
    const int* __restrict__ ei2, const float* __restrict__ ea2,
    const float* __restrict__ dinv_all, short* __restrict__ Lb,
    const float* __restrict__ x1, const float* __restrict__ x2,
    const short* __restrict__ WbT, float* __restrict__ Y,
    short* __restrict__ Y2t) {
  __shared__ __align__(16) char smem[34 * 288 * 4 + 272 * 4];  // 40,256 B
  int t = threadIdx.x;
  int bx = blockIdx.x;
  if (bx < 640) {
    // ===================== gemm1 (MFMA) =====================
    int xcd = bx & 7, rest = bx >> 3;       // rest 0..79
    int g = xcd + 8 * (rest / 5);           // graph on XCD g&7
    int m0 = (rest % 5) * 64;
    const float* A32 = (g < 64) ? (x1 + (size_t)g * NN * 268)
                                : (x2 + (size_t)(g - 64) * NN * 268);
    float* Yg = Y + (size_t)g * NN * 192;
    short* Y2tg = Y2t + (size_t)g * ARENA_SLAB_S;
    short (*As)[40] = (short(*)[40])smem;                     //  5,120 B
    short (*Bs)[40] = (short(*)[40])(smem + 64 * 40 * 2);     // 15,360 B
    int w = t >> 6, lane = t & 63;
    int quad = lane >> 4, l16 = lane & 15;
    int mh = w & 1, nh = w >> 1;
    f32x4 acc[2][6];
#pragma unroll
    for (int mi = 0; mi < 2; ++mi)
#pragma unroll
      for (int ni = 0; ni < 6; ++ni) acc[mi][ni] = (f32x4){0.f, 0.f, 0.f, 0.f};

    int sr = t >> 2, sko = (t & 3) * 8;
    for (int k0 = 0; k0 < KP; k0 += 32) {
      {
        int row = m0 + sr;
        int k = k0 + sko;
        float4 va = make_float4(0.f, 0.f, 0.f, 0.f), vb = va;
        if (row < NN && k < 268) va = *(const float4*)(A32 + (size_t)row * 268 + k);
        if (row < NN && k + 4 < 268) vb = *(const float4*)(A32 + (size_t)row * 268 + k + 4);
        short8 s;
        s[0] = f2bf(va.x); s[1] = f2bf(va.y); s[2] = f2bf(va.z); s[3] = f2bf(va.w);
        s[4] = f2bf(vb.x); s[5] = f2bf(vb.y); s[6] = f2bf(vb.z); s[7] = f2bf(vb.w);
        *(short8*)(&As[sr][sko]) = s;
      }
#pragma unroll
      for (int i = 0; i < 3; ++i) {
        int r = sr + i * 64;
        *(short8*)(&Bs[r][sko]) = *(const short8*)(WbT + (size_t)r * KP + k0 + sko);
      }
      __syncthreads();
      short8 af[2], bfr[6];
#pragma unroll
      for (int mi = 0; mi < 2; ++mi)
        af[mi] = *(const short8*)(&As[(mh * 2 + mi) * 16 + l16][quad * 8]);
#pragma unroll
      for (int ni = 0; ni < 6; ++ni)
        bfr[ni] = *(const short8*)(&Bs[(nh * 6 + ni) * 16 + l16][quad * 8]);
#pragma unroll
      for (int mi = 0; mi < 2; ++mi)
#pragma unroll
        for (int ni = 0; ni < 6; ++ni)
          acc[mi][ni] = __builtin_amdgcn_mfma_f32_16x16x32_bf16(af[mi], bfr[ni], acc[mi][ni], 0, 0, 0);
      __syncthreads();
    }
    // C/D: col = lane&15, row = quad*4 + reg
#pragma unroll
    for (int mi = 0; mi < 2; ++mi) {
      int rbase = m0 + (mh * 2 + mi) * 16 + quad * 4;
#pragma unroll
      for (int reg = 0; reg < 4; ++reg) {
        int row = rbase + reg;
        if (row < NN) {
#pragma unroll
          for (int ni = 0; ni < 6; ++ni) {
            int col = (nh * 6 + ni) * 16 + l16;
            Yg[(size_t)row * 192 + col] = acc[mi][ni][reg];
          }
        }
      }
      if (rbase < NN) {  // rbase % 4 == 0, never straddles 268
#pragma unroll
        for (int ni = 0; ni < 6; ++ni) {
          int col = (nh * 6 + ni) * 16 + l16;
          if (col >= 128) {
            short4v p;
#pragma unroll
            for (int reg = 0; reg < 4; ++reg) p[reg] = f2bf(acc[mi][ni][reg]);
            *(short4v*)(Y2tg + (size_t)(col - 128) * KP + rbase) = p;
          }
        }
      }
    }
  } else {
    // ===================== Laplacian build =====================
    int l = bx - 640;                // 0..1023 = 8 xcd * 16 g * 8 tiles
    int xcd = l & 7, rest = l >> 3;  // rest 0..127
    int g = xcd + 8 * (rest & 15);
    int tile = rest >> 4;            // 0..7
    int r0 = tile * 34;
    const int* ei = (g < 64) ? (ei1 + (size_t)g * 2 * NE) : (ei2 + (size_t)(g - 64) * 2 * NE);
    const float* ea = (g < 64) ? (ea1 + (size_t)g * NE) : (ea2 + (size_t)(g - 64) * NE);
    int* LrowI = (int*)smem;                      // 34*288 ints = 39,168 B
    float* dv = (float*)(smem + 39168);           // 272 floats
    for (int i = t; i < 34 * 288; i += 256) LrowI[i] = 0;
    for (int i = t; i < 272; i += 256) dv[i] = dinv_all[(size_t)g * 272 + i];
    __syncthreads();
#pragma unroll 8
    for (int e = t; e < NE; e += 256) {
      int d = ei[NE + e];
      int s = ei[e];
      float w = ea[e];
      if (d >= r0 && d < r0 + 34 && s != d) {
        atomicAdd(&LrowI[(d - r0) * 288 + s],
                  (int)lrintf(-dv[s] * w * dv[d] * 16777216.f));  // native ds_add
      }
    }
    __syncthreads();
    short* Lbg = Lb + (size_t)g * 272 * KP + (size_t)r0 * KP;
    for (int i = t; i < 34 * 288; i += 256)
      Lbg[i] = f2bf((float)LrowI[i] * (1.f / 16777216.f));
  }
}

// ---------------------------------------------------------------------------
// K3: MEGA — whole post-gemm1 chain per graph in ONE block. Round-5 version:
// 512 threads (8 waves, 2/SIMD — 2x TLP of round 4), explicit register
// double-buffer of the global L A-fragments, and residual-Y prefetch into
// registers before each tile's MFMA cluster. 128 blocks, 111,616 B LDS.
// Phases (identical math to round 4):
//   P0 Y2t->LDS   P1 Ut=bf16(Y1+2*L@Y2)   P2 H1=relu(Y0-Y2+L@Ut+b1)
//   P3 Yb=H1@W4 -> Yg f32 + Yb2t LDS      P4 Ut2=bf16(Yb1+2*L@Yb2)
//   P5 H2=relu(Yb0-Yb2+L@Ut2+b4)          P6 classifier -> out
// ---------------------------------------------------------------------------
#define SP 296
#define YT2_O  0
#define H1N_O  0
#define UT_O   40960
#define UT2_O  40960
#define H2T_O  59904
#define W4S_O  78848
#define YBT_O  92672
#define Z1_O   0
#define W2S_O  14848
#define Z2_O   78848
#define W3S_O  87040
#define SM_SZ  111616
#define NW     8       // waves per mega block

__device__ __forceinline__ void load_a9(const short* __restrict__ Lbg,
                                        int mt, int l16, int quad, short8* a9) {
  const short* Arow = Lbg + (size_t)(mt * 16 + l16) * KP + quad * 8;
#pragma unroll
  for (int k = 0; k < 9; ++k) a9[k] = *(const short8*)(Arow + k * 32);
}

template <int NTN>
__device__ __forceinline__ void cheb_mm_pre(const short8* a9,
                                            const char* B0, int l16, int quad,
                                            f32x4* acc) {
#pragma unroll
  for (int k = 0; k < 9; ++k) {
#pragma unroll
    for (int nt = 0; nt < NTN; ++nt) {
      short8 bf = *(const short8*)(B0 +
          ((size_t)(nt * 16 + l16) * SP + k * 32 + quad * 8) * 2);
      acc[nt] = __builtin_amdgcn_mfma_f32_16x16x32_bf16(a9[k], bf, acc[nt], 0, 0, 0);
    }
  }
}

__global__ __launch_bounds__(512, 1) void k_mega(
    const short* __restrict__ Lb, const short* __restrict__ arena,
    float* __restrict__ Y, const short* __restrict__ W4bT,
    const short* __restrict__ Wc1bT,
    const float* __restrict__ b1, const float* __restrict__ b4,
    const float* __restrict__ bc1, const float* __restrict__ Wc2,
    const float* __restrict__ bc2, const float* __restrict__ Wc3,
    const float* __restrict__ bc3, float* __restrict__ out) {
  __shared__ __align__(16) char sm[SM_SZ];
  int g = blockIdx.x;
  int t = threadIdx.x;
  int w = t >> 6, lane = t & 63;
  int quad = lane >> 4, l16 = lane & 15;
  const short* Lbg = Lb + (size_t)g * 272 * KP;
  const short* Y2tg = arena + (size_t)g * ARENA_SLAB_S;
  float* Yg = Y + (size_t)g * NN * 192;

  // ---- P0: Y2t -> LDS [64][SP]; cols >=268 forced to 0 (poison-safe) ----
  for (int i = t; i < 64 * 37; i += 512) {
    int r = i / 37, c = (i - r * 37) * 8;
    short8 v = {0, 0, 0, 0, 0, 0, 0, 0};
    if (c < 264) {
      v = *(const short8*)(Y2tg + (size_t)r * KP + c);
    } else if (c == 264) {
      v = *(const short8*)(Y2tg + (size_t)r * KP + 264);
      v[4] = 0; v[5] = 0; v[6] = 0; v[7] = 0;
    }
    *(short8*)(sm + YT2_O + ((size_t)r * SP + c) * 2) = v;
  }
  // zero Ut node-pad cols 268..287 (before barrier; Ut region disjoint of Y2t)
  for (int i = t; i < 64 * 20; i += 512) {
    int f = i / 20, d = 268 + (i - f * 20);
    *(short*)(sm + UT_O + ((size_t)f * SP + d) * 2) = 0;
  }
  __syncthreads();

  // ---- P1: Ut[f][d] = bf16(Y1[d][f] + 2*(L@Y2)[d][f]) ----
  {
    short8 ac[9], an[9];
    int mt = w;
    if (mt < 17) load_a9(Lbg, mt, l16, quad, ac);
    for (; mt < 17; mt += NW) {
      if (mt + NW < 17) load_a9(Lbg, mt + NW, l16, quad, an);
      int dbase = mt * 16 + quad * 4;
      float yr[4][4];
      if (dbase < NN) {
#pragma unroll
        for (int nt = 0; nt < 4; ++nt)
#pragma unroll
          for (int reg = 0; reg < 4; ++reg)
            yr[nt][reg] = Yg[(size_t)(dbase + reg) * 192 + 64 + nt * 16 + l16];
      }
      f32x4 acc[4];
#pragma unroll
      for (int nt = 0; nt < 4; ++nt) acc[nt] = (f32x4){0.f, 0.f, 0.f, 0.f};
      cheb_mm_pre<4>(ac, sm + YT2_O, l16, quad, acc);
      if (dbase < NN) {
#pragma unroll
        for (int nt = 0; nt < 4; ++nt) {
          int f = nt * 16 + l16;
          short4v p;
#pragma unroll
          for (int reg = 0; reg < 4; ++reg)
            p[reg] = f2bf(yr[nt][reg] + 2.f * acc[nt][reg]);
          *(short4v*)(sm + UT_O + ((size_t)f * SP + dbase) * 2) = p;
        }
      }
      if (mt + NW < 17) {
#pragma unroll
        for (int k = 0; k < 9; ++k) ac[k] = an[k];
      }
    }
  }
  __syncthreads();

  // ---- P2: H1n[d][f] = relu(Y0 - Y2 + (L@Ut)[d][f] + b1[f]), stride 72 ----
  {
    short8 ac[9], an[9];
    int mt = w;
    if (mt < 17) load_a9(Lbg, mt, l16, quad, ac);
    for (; mt < 17; mt += NW) {
      if (mt + NW < 17) load_a9(Lbg, mt + NW, l16, quad, an);
      int dbase = mt * 16 + quad * 4;
      float yr0[4][4], yr2[4][4];
      if (dbase < NN) {
#pragma unroll
        for (int nt = 0; nt < 4; ++nt)
#pragma unroll
          for (int reg = 0; reg < 4; ++reg) {
            int f = nt * 16 + l16;
            yr0[nt][reg] = Yg[(size_t)(dbase + reg) * 192 + f];
            yr2[nt][reg] = Yg[(size_t)(dbase + reg) * 192 + 128 + f];
          }
      }
      f32x4 acc[4];
#pragma unroll
      for (int nt = 0; nt < 4; ++nt) acc[nt] = (f32x4){0.f, 0.f, 0.f, 0.f};
      cheb_mm_pre<4>(ac, sm + UT_O, l16, quad, acc);
      if (dbase < NN) {
#pragma unroll
        for (int nt = 0; nt < 4; ++nt) {
          int f = nt * 16 + l16;
          float bb = b1[f];
#pragma unroll
          for (int reg = 0; reg < 4; ++reg) {
            int d = dbase + reg;
            float v = yr0[nt][reg] - yr2[nt][reg] + acc[nt][reg] + bb;
            *(short*)(sm + H1N_O + ((size_t)d * 72 + f) * 2) = f2bf(fmaxf(v, 0.f));
          }
        }
      }
      if (mt + NW < 17) {
#pragma unroll
        for (int k = 0; k < 9; ++k) ac[k] = an[k];
      }
    }
  }
  __syncthreads();

  // ---- P3: Yb^T[c][d] = (H1 @ W4)[d][c]; c<64 -> Yg[d][c] f32,
  //          c>=64 -> Yg[d][c+96] f32 + YBT (Yb2t bf16) ----
  for (int i = t; i < 96 * 8; i += 512) {   // stage W4s [96][72]
    int r = i >> 3, ko = (i & 7) * 8;
    *(short8*)(sm + W4S_O + ((size_t)r * 72 + ko) * 2) =
        *(const short8*)(W4bT + r * 64 + ko);
  }
  for (int i = t; i < 32 * 20; i += 512) {  // zero YBT node-pads
    int f = i / 20, d = 268 + (i - f * 20);
    *(short*)(sm + YBT_O + ((size_t)f * SP + d) * 2) = 0;
  }
  __syncthreads();
  for (int id = w; id < 102; id += NW) {    // 6 c-tiles x 17 d-tiles
    int mt = id / 17, nt = id - mt * 17;
    f32x4 a1 = (f32x4){0.f, 0.f, 0.f, 0.f};
#pragma unroll
    for (int kc = 0; kc < 2; ++kc) {
      short8 af = *(const short8*)(sm + W4S_O +
          ((size_t)(mt * 16 + l16) * 72 + kc * 32 + quad * 8) * 2);
      short8 bf = *(const short8*)(sm + H1N_O +
          ((size_t)(nt * 16 + l16) * 72 + kc * 32 + quad * 8) * 2);
      a1 = __builtin_amdgcn_mfma_f32_16x16x32_bf16(af, bf, a1, 0, 0, 0);
    }
    int d = nt * 16 + l16;
    if (d < NN) {
      int c0 = mt * 16 + quad * 4;
#pragma unroll
      for (int reg = 0; reg < 4; ++reg) {
        int c = c0 + reg;
        float a = a1[reg];
        Yg[(size_t)d * 192 + ((c < 64) ? c : c + 96)] = a;
        if (c >= 64)
          *(short*)(sm + YBT_O + ((size_t)(c - 64) * SP + d) * 2) = f2bf(a);
      }
    }
  }
  __syncthreads();

  // ---- P4: Ut2[f][d] = bf16(Yb1[d][f] + 2*(L@Yb2)[d][f]) ----
  for (int i = t; i < 32 * 20; i += 512) {
    int f = i / 20, d = 268 + (i - f * 20);
    *(short*)(sm + UT2_O + ((size_t)f * SP + d) * 2) = 0;
  }
  __syncthreads();
  {
    short8 ac[9], an[9];
    int mt = w;
    if (mt < 17) load_a9(Lbg, mt, l16, quad, ac);
    for (; mt < 17; mt += NW) {
      if (mt + NW < 17) load_a9(Lbg, mt + NW, l16, quad, an);
      int dbase = mt * 16 + quad * 4;
      float yr[2][4];
      if (dbase < NN) {
#pragma unroll
        for (int nt = 0; nt < 2; ++nt)
#pragma unroll
          for (int reg = 0; reg < 4; ++reg)
            yr[nt][reg] = Yg[(size_t)(dbase + reg) * 192 + 32 + nt * 16 + l16];
      }
      f32x4 acc[2];
#pragma unroll
      for (int nt = 0; nt < 2; ++nt) acc[nt] = (f32x4){0.f, 0.f, 0.f, 0.f};
      cheb_mm_pre<2>(ac, sm + YBT_O, l16, quad, acc);
      if (dbase < NN) {
#pragma unroll
        for (int nt = 0; nt < 2; ++nt) {
          int f = nt * 16 + l16;
          short4v p;
#pragma unroll
          for (int reg = 0; reg < 4; ++reg)
            p[reg] = f2bf(yr[nt][reg] + 2.f * acc[nt][reg]);
          *(short4v*)(sm + UT2_O + ((size_t)f * SP + dbase) * 2) = p;
        }
      }
      if (mt + NW < 17) {
#pragma unroll
        for (int k = 0; k < 9; ++k) ac[k] = an[k];
      }
    }
  }
  __syncthreads();

  // ---- P5: H2T[f][d] = relu(Yb0 - Yb2 + (L@Ut2)[d][f] + b4[f]) ----
  for (int i = t; i < 32 * 20; i += 512) {
    int f = i / 20, d = 268 + (i - f * 20);
    *(short*)(sm + H2T_O + ((size_t)f * SP + d) * 2) = 0;
  }
  __syncthreads();
  {
    short8 ac[9], an[9];
    int mt = w;
    if (mt < 17) load_a9(Lbg, mt, l16, quad, ac);
    for (; mt < 17; mt += NW) {
      if (mt + NW < 17) load_a9(Lbg, mt + NW, l16, quad, an);
      int dbase = mt * 16 + quad * 4;
      float yr0[2][4], yr2[2][4];
      if (dbase < NN) {
#pragma unroll
        for (int nt = 0; nt < 2; ++nt)
#pragma unroll
          for (int reg = 0; reg < 4; ++reg) {
            int f = nt * 16 + l16;
            yr0[nt][reg] = Yg[(size_t)(dbase + reg) * 192 + f];
            yr2[nt][reg] = Yg[(size_t)(dbase + reg) * 192 + 160 + f];
          }
      }
      f32x4 acc[2];
#pragma unroll
      for (int nt = 0; nt < 2; ++nt) acc[nt] = (f32x4){0.f, 0.f, 0.f, 0.f};
      cheb_mm_pre<2>(ac, sm + UT2_O, l16, quad, acc);
      if (dbase < NN) {
#pragma unroll
        for (int nt = 0; nt < 2; ++nt) {
          int f = nt * 16 + l16;
          float bb = b4[f];
          short4v p;
#pragma unroll
          for (int reg = 0; reg < 4; ++reg) {
            float v = yr0[nt][reg] - yr2[nt][reg] + acc[nt][reg] + bb;
            p[reg] = f2bf(fmaxf(v, 0.f));
          }
          *(short4v*)(sm + H2T_O + ((size_t)f * SP + dbase) * 2) = p;
        }
      }
      if (mt + NW < 17) {
#pragma unroll
        for (int k = 0; k < 9; ++k) ac[k] = an[k];
      }
    }
  }
  __syncthreads();

  // ---- P6: classifier. L1: MFMA 32x112 K=288 (A=H2T LDS, B=Wc1bT global) ----
  for (int id = w; id < 14; id += NW) {     // 2 m-tiles x 7 n-tiles
    int mt = id & 1, nt = id >> 1;
    f32x4 a1 = (f32x4){0.f, 0.f, 0.f, 0.f};
#pragma unroll
    for (int k = 0; k < 9; ++k) {
      short8 af = *(const short8*)(sm + H2T_O +
          ((size_t)(mt * 16 + l16) * SP + k * 32 + quad * 8) * 2);
      short8 bf = *(const short8*)(Wc1bT + (size_t)(nt * 16 + l16) * KP + k * 32 + quad * 8);
      a1 = __builtin_amdgcn_mfma_f32_16x16x32_bf16(af, bf, a1, 0, 0, 0);
    }
    int col = nt * 16 + l16;
    if (col < 100) {
      float bb = bc1[col];
      int r0 = mt * 16 + quad * 4;
#pragma unroll
      for (int reg = 0; reg < 4; ++reg)
        *(float*)(sm + Z1_O + ((size_t)(r0 + reg) * 116 + col) * 4) =
            fmaxf(a1[reg] + bb, 0.f);
    }
  }
  for (int i = t; i < 100 * 64; i += 512) {  // stage W2s [100][64]
    int rr = i >> 6, c = i & 63;
    *(float*)(sm + W2S_O + ((size_t)rr * 64 + c) * 4) =
        (c < 60) ? Wc2[(size_t)rr * 60 + c] : 0.f;
  }
  if (t < 64) *(float*)(sm + W3S_O + (size_t)t * 4) = (t < 60) ? Wc3[t] : 0.f;
  __syncthreads();
  if (t < 128) {                             // L2: Z2 = relu(Z1@Wc2+bc2)
    int r2 = (t >> 3) * 2;
    int c8 = (t & 7) * 8;
    float a2[2][8];
#pragma unroll
    for (int i = 0; i < 2; ++i)
#pragma unroll
      for (int j = 0; j < 8; ++j) a2[i][j] = 0.f;
    const float* Z1p = (const float*)(sm + Z1_O);
    const float* W2p = (const float*)(sm + W2S_O);
#pragma unroll 4
    for (int k = 0; k < 100; ++k) {
      float x0 = Z1p[(size_t)r2 * 116 + k], x1 = Z1p[(size_t)(r2 + 1) * 116 + k];
      float4 wA = *(const float4*)(W2p + (size_t)k * 64 + c8);
      float4 wB = *(const float4*)(W2p + (size_t)k * 64 + c8 + 4);
      float wv[8] = {wA.x, wA.y, wA.z, wA.w, wB.x, wB.y, wB.z, wB.w};
#pragma unroll
      for (int j = 0; j < 8; ++j) { a2[0][j] += x0 * wv[j]; a2[1][j] += x1 * wv[j]; }
    }
    float* Z2p = (float*)(sm + Z2_O);
#pragma unroll
    for (int j = 0; j < 8; ++j) {
      int c = c8 + j;
      float bb = (c < 60) ? bc2[c] : 0.f;
      Z2p[(size_t)r2 * 64 + c] = fmaxf(a2[0][j] + bb, 0.f);
      Z2p[(size_t)(r2 + 1) * 64 + c] = fmaxf(a2[1][j] + bb, 0.f);
    }
  }
  __syncthreads();
  if (t < 32) {                              // L3: out = Z2 . Wc3 + bc3
    const float* Z2p = (const float*)(sm + Z2_O);
    const float* w3p = (const float*)(sm + W3S_O);
    float acc3 = bc3[0];
#pragma unroll
    for (int k = 0; k < 60; ++k) acc3 += Z2p[(size_t)t * 64 + k] * w3p[k];
    out[(size_t)g * 32 + t] = acc3;
  }
}

extern "C" void kernel_launch(void* const* d_in, const int* in_sizes, int n_in,
                              void* d_out, int out_size, void* d_ws, size_t ws_size,
                              hipStream_t stream) {
  (void)in_sizes; (void)n_in; (void)out_size; (void)ws_size;
  const float* x1  = (const float*)d_in[0];
  const int*   ei1 = (const int*)d_in[1];
  const float* ea1 = (const float*)d_in[2];
  const float* x2  = (const float*)d_in[3];
  const int*   ei2 = (const int*)d_in[4];
  const float* ea2 = (const float*)d_in[5];
  const float* W1  = (const float*)d_in[6];
  const float* b1  = (const float*)d_in[7];
  const float* W4  = (const float*)d_in[8];
  const float* b4  = (const float*)d_in[9];
  const float* Wc1 = (const float*)d_in[10];
  const float* bc1 = (const float*)d_in[11];
  const float* Wc2 = (const float*)d_in[12];
  const float* bc2 = (const float*)d_in[13];
  const float* Wc3 = (const float*)d_in[14];
  const float* bc3 = (const float*)d_in[15];

  char* ws = (char*)d_ws;
  float* dinv  = (float*)(ws + OFF_DINV);
  short* arena = (short*)(ws + OFF_ARENA);
  short* WbT   = (short*)(ws + OFF_WBT);
  short* Wc1bT = (short*)(ws + OFF_WC1BT);
  short* W4bT  = (short*)(ws + OFF_W4BT);
  short* Lb    = (short*)(ws + OFF_LB);
  float* Y     = (float*)(ws + OFF_Y);
  float* out   = (float*)d_out;

  // L1: dinv + weight conversions (round-1 verbatim)
  k_prep<<<494, 256, 0, stream>>>(ei1, ea1, ei2, ea2, W1, Wc1, W4,
                                  WbT, Wc1bT, W4bT, dinv);
  // L2: dense Laplacian build || gemm1 (round-1 verbatim, measured 48 us)
  k_build_gemm1<<<1664, 256, 0, stream>>>(ei1, ea1, ei2, ea2, dinv, Lb,
                                          x1, x2, WbT, Y, arena);
  // L3: per-graph mega-block, 512 threads + reg-prefetch latency hiding
  k_mega<<<128, 512, 0, stream>>>(Lb, arena, Y, W4bT, Wc1bT,
                                  b1, b4, bc1, Wc2, bc2, Wc3, bc3, out);
}